// Round 2
// baseline (3516.703 us; speedup 1.0000x reference)
//
#include <hip/hip_runtime.h>
#include <hip/hip_bf16.h>

#define H 256
#define TM 32
#define LN_EPS 1e-5f

// Register-tiled GEMM core: out[32][256] = sA[32][256] @ W[256][256].
// 256 threads: lane_j = tid&63 (cols j = lane_j + 64*cc), rg = tid>>6 (rows rg*8..rg*8+7).
// All 64 lanes of a wave share rg -> LDS reads are same-address broadcasts (conflict-free).
__device__ __forceinline__ void gemm_tile(const float* __restrict__ sA,
                                          const float* __restrict__ W,
                                          int lane_j, int rg, float acc[8][4]) {
#pragma unroll
  for (int mm = 0; mm < 8; mm++)
#pragma unroll
    for (int cc = 0; cc < 4; cc++) acc[mm][cc] = 0.f;
  for (int k = 0; k < H; k += 4) {
    float tvf[8][4];
#pragma unroll
    for (int mm = 0; mm < 8; mm++)
      *(float4*)&tvf[mm][0] = *(const float4*)&sA[(rg * 8 + mm) * H + k];
#pragma unroll
    for (int kk = 0; kk < 4; kk++) {
      const float* wr = W + (k + kk) * H + lane_j;
      float w0 = wr[0], w1 = wr[64], w2 = wr[128], w3 = wr[192];
#pragma unroll
      for (int mm = 0; mm < 8; mm++) {
        float av = tvf[mm][kk];
        acc[mm][0] = fmaf(av, w0, acc[mm][0]);
        acc[mm][1] = fmaf(av, w1, acc[mm][1]);
        acc[mm][2] = fmaf(av, w2, acc[mm][2]);
        acc[mm][3] = fmaf(av, w3, acc[mm][3]);
      }
    }
  }
}

// ---------- kernels ----------

// Detect whether edge_index arrived as int64 (odd int32 words all zero) or int32.
__global__ void k_detect(const int* __restrict__ ei, int* __restrict__ flag) {
  if (threadIdx.x == 0 && blockIdx.x == 0)
    *flag = (ei[1] == 0 && ei[3] == 0 && ei[5] == 0 && ei[7] == 0) ? 1 : 0;
}

// Zero a float buffer (avoids hipMemsetAsync inside graph capture).
__global__ __launch_bounds__(256) void k_zero(float4* __restrict__ p, int n4) {
  int i = blockIdx.x * 256 + threadIdx.x;
  if (i < n4) p[i] = make_float4(0.f, 0.f, 0.f, 0.f);
}

// h = relu([x, a] @ np_w + np_b), one block per node, thread per column.
__global__ __launch_bounds__(256) void k_node_proj(
    const float* __restrict__ x, const int* __restrict__ a,
    const float* __restrict__ w, const float* __restrict__ b,
    float* __restrict__ h, int N) {
  int node = blockIdx.x;
  int j = threadIdx.x;
  float acc = b[j];
  acc = fmaf(x[node * 3 + 0], w[0 * H + j], acc);
  acc = fmaf(x[node * 3 + 1], w[1 * H + j], acc);
  acc = fmaf(x[node * 3 + 2], w[2 * H + j], acc);
  acc = fmaf((float)a[node], w[3 * H + j], acc);
  h[(size_t)node * H + j] = fmaxf(acc, 0.f);
}

// W_comb[l] = em_w2 @ lin_w[l]   (one 32-row tile per block; 3 layers x 8 tiles)
__global__ __launch_bounds__(256, 2) void k_wcomb(
    const float* __restrict__ w2, const float* __restrict__ lin_w,
    float* __restrict__ wc) {
  __shared__ __align__(16) float sA[TM * H];
  int l = blockIdx.x >> 3, tile = blockIdx.x & 7;
  int tid = threadIdx.x;
  const float4* src = (const float4*)(w2 + (size_t)tile * TM * H);
#pragma unroll
  for (int it = 0; it < 8; it++) {
    int vi = it * 256 + tid;
    *(float4*)&sA[vi * 4] = src[vi];
  }
  __syncthreads();
  int lane_j = tid & 63, rg = tid >> 6;
  float acc[8][4];
  gemm_tile(sA, lin_w + (size_t)l * H * H, lane_j, rg, acc);
  float* out = wc + (size_t)l * H * H + (size_t)tile * TM * H;
#pragma unroll
  for (int cc = 0; cc < 4; cc++)
#pragma unroll
    for (int mm = 0; mm < 8; mm++)
      out[(rg * 8 + mm) * H + lane_j + 64 * cc] = acc[mm][cc];
}

// beta[l] = em_b2 @ lin_w[l] + lin_b[l]
__global__ __launch_bounds__(256) void k_beta(
    const float* __restrict__ lin_w, const float* __restrict__ lin_b,
    const float* __restrict__ b2, float* __restrict__ beta) {
  int l = blockIdx.x, j = threadIdx.x;
  const float* W = lin_w + (size_t)l * H * H;
  float v = lin_b[l * H + j];
  for (int k = 0; k < H; k++) v = fmaf(b2[k], W[k * H + j], v);
  beta[l * H + j] = v;
}

// Per layer: t = relu(ea@em_w1+em_b1); e_l = t@W_comb+beta;
// msg = relu(h[src]+e_l); atomicAdd agg[dst].
__global__ __launch_bounds__(256, 2) void k_edge_layer(
    const float* __restrict__ ea,
    const float* __restrict__ w1, const float* __restrict__ b1,
    const float* __restrict__ wc, const float* __restrict__ beta,
    const float* __restrict__ h, float* __restrict__ agg,
    const void* __restrict__ ei, const int* __restrict__ flag64, int E) {
  __shared__ __align__(16) float sA[TM * H];
  __shared__ float sEA[TM * 4];
  __shared__ int sSrc[TM];
  __shared__ int sDst[TM];
  int tid = threadIdx.x;
  int base = blockIdx.x * TM;
  int is64 = *flag64;
  if (tid < TM * 4) {
    sEA[tid] = ea[(size_t)base * 4 + tid];
  } else if (tid < 128 + TM) {
    int t = tid - 128;
    long long v = is64 ? ((const long long*)ei)[base + t]
                       : (long long)((const int*)ei)[base + t];
    sSrc[t] = (int)v;
  } else if (tid < 160 + TM) {
    int t = tid - 160;
    long long v = is64 ? ((const long long*)ei)[(size_t)E + base + t]
                       : (long long)((const int*)ei)[(size_t)E + base + t];
    sDst[t] = (int)v;
  }
  __syncthreads();
  {  // t = relu(ea @ w1 + b1) -> sA, thread per column
    int j = tid;
    float c0 = w1[0 * H + j], c1 = w1[1 * H + j], c2 = w1[2 * H + j], c3 = w1[3 * H + j];
    float bj = b1[j];
#pragma unroll
    for (int m = 0; m < TM; m++) {
      float v = bj;
      v = fmaf(sEA[m * 4 + 0], c0, v);
      v = fmaf(sEA[m * 4 + 1], c1, v);
      v = fmaf(sEA[m * 4 + 2], c2, v);
      v = fmaf(sEA[m * 4 + 3], c3, v);
      sA[m * H + j] = fmaxf(v, 0.f);
    }
  }
  __syncthreads();
  int lane_j = tid & 63, rg = tid >> 6;
  float acc[8][4];
  gemm_tile(sA, wc, lane_j, rg, acc);
  float bv[4];
#pragma unroll
  for (int cc = 0; cc < 4; cc++) bv[cc] = beta[lane_j + 64 * cc];
#pragma unroll
  for (int mm = 0; mm < 8; mm++) {
    int m = rg * 8 + mm;
    const float* hrow = h + (size_t)sSrc[m] * H;
    float* arow = agg + (size_t)sDst[m] * H;
#pragma unroll
    for (int cc = 0; cc < 4; cc++) {
      int j = lane_j + 64 * cc;
      float msg = fmaxf(hrow[j] + acc[mm][cc] + bv[cc], 0.f);
      atomicAdd(&arow[j], msg);
    }
  }
}

// Per layer: z = h+agg; z = relu(z@w1+b1)@w2+b2; LN; h += relu(LN)
__global__ __launch_bounds__(256, 2) void k_node_mlp(
    float* __restrict__ h, const float* __restrict__ agg,
    const float* __restrict__ w1, const float* __restrict__ b1,
    const float* __restrict__ w2, const float* __restrict__ b2,
    const float* __restrict__ lng, const float* __restrict__ lnb) {
  __shared__ __align__(16) float sA[TM * H];
  __shared__ __align__(16) float sB[TM * H];
  int tid = threadIdx.x;
  int base = blockIdx.x * TM;
  const float4* h4 = (const float4*)(h + (size_t)base * H);
  const float4* a4 = (const float4*)(agg + (size_t)base * H);
#pragma unroll
  for (int it = 0; it < 8; it++) {
    int vi = it * 256 + tid;  // 2048 float4 total
    float4 hv = h4[vi], av = a4[vi];
    float4 z;
    z.x = hv.x + av.x; z.y = hv.y + av.y; z.z = hv.z + av.z; z.w = hv.w + av.w;
    *(float4*)&sA[vi * 4] = z;
  }
  __syncthreads();
  int lane_j = tid & 63, rg = tid >> 6;
  float acc[8][4];
  gemm_tile(sA, w1, lane_j, rg, acc);
#pragma unroll
  for (int cc = 0; cc < 4; cc++) {
    float bv = b1[lane_j + 64 * cc];
#pragma unroll
    for (int mm = 0; mm < 8; mm++)
      sB[(rg * 8 + mm) * H + lane_j + 64 * cc] = fmaxf(acc[mm][cc] + bv, 0.f);
  }
  __syncthreads();
  gemm_tile(sB, w2, lane_j, rg, acc);
  float gv[4], bv2[4], b2v[4];
#pragma unroll
  for (int cc = 0; cc < 4; cc++) {
    int j = lane_j + 64 * cc;
    gv[cc] = lng[j]; bv2[cc] = lnb[j]; b2v[cc] = b2[j];
  }
#pragma unroll
  for (int mm = 0; mm < 8; mm++) {
    float z2[4];
    float s = 0.f, ss = 0.f;
#pragma unroll
    for (int cc = 0; cc < 4; cc++) {
      z2[cc] = acc[mm][cc] + b2v[cc];
      s += z2[cc];
      ss = fmaf(z2[cc], z2[cc], ss);
    }
#pragma unroll
    for (int off = 32; off > 0; off >>= 1) {
      s += __shfl_xor(s, off, 64);
      ss += __shfl_xor(ss, off, 64);
    }
    float mu = s * (1.f / H);
    float var = ss * (1.f / H) - mu * mu;
    float rstd = rsqrtf(var + LN_EPS);
    int m = rg * 8 + mm;
    float* hr = h + (size_t)(base + m) * H;
#pragma unroll
    for (int cc = 0; cc < 4; cc++) {
      int j = lane_j + 64 * cc;
      float v = fmaf((z2[cc] - mu) * rstd, gv[cc], bv2[cc]);
      hr[j] = hr[j] + fmaxf(v, 0.f);
    }
  }
}

// Mean-pool per graph + head MLP. One block per graph.
__global__ __launch_bounds__(256) void k_pool_head(
    const float* __restrict__ h,
    const float* __restrict__ w1, const float* __restrict__ b1,
    const float* __restrict__ w2, const float* __restrict__ b2,
    float* __restrict__ out, int n) {
  __shared__ float sG[H];
  __shared__ float sT[H];
  __shared__ float sR[4];
  int b = blockIdx.x, tid = threadIdx.x;
  const float* hb = h + (size_t)b * n * H;
  float a0 = 0.f, a1 = 0.f, a2 = 0.f, a3 = 0.f;
  for (int i = 0; i < n; i += 4) {
    a0 += hb[(size_t)(i + 0) * H + tid];
    a1 += hb[(size_t)(i + 1) * H + tid];
    a2 += hb[(size_t)(i + 2) * H + tid];
    a3 += hb[(size_t)(i + 3) * H + tid];
  }
  sG[tid] = (a0 + a1 + a2 + a3) / (float)n;
  __syncthreads();
  float t = b1[tid];
  for (int k = 0; k < H; k++) t = fmaf(sG[k], w1[k * H + tid], t);
  sT[tid] = fmaxf(t, 0.f);
  __syncthreads();
  float p = sT[tid] * w2[tid];
#pragma unroll
  for (int off = 32; off > 0; off >>= 1) p += __shfl_xor(p, off, 64);
  if ((tid & 63) == 0) sR[tid >> 6] = p;
  __syncthreads();
  if (tid == 0) out[b] = sR[0] + sR[1] + sR[2] + sR[3] + b2[0];
}

// ---------- launcher ----------
extern "C" void kernel_launch(void* const* d_in, const int* in_sizes, int n_in,
                              void* d_out, int out_size, void* d_ws, size_t ws_size,
                              hipStream_t stream) {
  const float* x      = (const float*)d_in[0];
  const float* ea     = (const float*)d_in[1];
  const void*  ei     = d_in[2];
  const int*   a      = (const int*)d_in[3];
  const float* np_w   = (const float*)d_in[4];
  const float* np_b   = (const float*)d_in[5];
  const float* em_w1  = (const float*)d_in[6];
  const float* em_b1  = (const float*)d_in[7];
  const float* em_w2  = (const float*)d_in[8];
  const float* em_b2  = (const float*)d_in[9];
  const float* lin_w  = (const float*)d_in[10];
  const float* lin_b  = (const float*)d_in[11];
  const float* m_w1   = (const float*)d_in[12];
  const float* m_b1   = (const float*)d_in[13];
  const float* m_w2   = (const float*)d_in[14];
  const float* m_b2   = (const float*)d_in[15];
  const float* ln_g   = (const float*)d_in[16];
  const float* ln_b   = (const float*)d_in[17];
  const float* hd_w1  = (const float*)d_in[18];
  const float* hd_b1  = (const float*)d_in[19];
  const float* hd_w2  = (const float*)d_in[20];
  const float* hd_b2  = (const float*)d_in[21];

  int N = in_sizes[0] / 3;
  int E = in_sizes[1] / 4;
  int B = out_size;
  int n = N / B;

  // workspace layout (~68 MB total)
  char* ws = (char*)d_ws;
  float* h      = (float*)ws;                                    // N*H*4 = 33.5 MB
  float* agg    = (float*)(ws + (size_t)N * H * 4);              // N*H*4 = 33.5 MB
  float* wcomb  = (float*)(ws + (size_t)N * H * 8);              // 3*H*H*4 = 786 KB
  float* beta   = (float*)(ws + (size_t)N * H * 8 + 3 * H * H * 4);  // 3*H*4
  int*   flag   = (int*)(ws + (size_t)N * H * 8 + 3 * H * H * 4 + 3 * H * 4);

  float* out = (float*)d_out;

  k_detect<<<1, 64, 0, stream>>>((const int*)ei, flag);
  k_node_proj<<<N, 256, 0, stream>>>(x, a, np_w, np_b, h, N);
  k_wcomb<<<24, 256, 0, stream>>>(em_w2, lin_w, wcomb);
  k_beta<<<3, 256, 0, stream>>>(lin_w, lin_b, em_b2, beta);

  int n4 = N * H / 4;
  for (int l = 0; l < 3; l++) {
    k_zero<<<(n4 + 255) / 256, 256, 0, stream>>>((float4*)agg, n4);
    k_edge_layer<<<E / TM, 256, 0, stream>>>(ea, em_w1, em_b1,
                                             wcomb + (size_t)l * H * H,
                                             beta + (size_t)l * H,
                                             h, agg, ei, flag, E);
    k_node_mlp<<<N / TM, 256, 0, stream>>>(h, agg, m_w1 + (size_t)l * H * H,
                                           m_b1 + (size_t)l * H,
                                           m_w2 + (size_t)l * H * H,
                                           m_b2 + (size_t)l * H,
                                           ln_g + (size_t)l * H, ln_b + (size_t)l * H);
  }
  k_pool_head<<<B, 256, 0, stream>>>(h, hd_w1, hd_b1, hd_w2, hd_b2, out, n);
}

// Round 5
// 3168.159 us; speedup vs baseline: 1.1100x; 1.1100x over previous
//
#include <hip/hip_runtime.h>
#include <hip/hip_bf16.h>

#define H 256
#define LN_EPS 1e-5f
#define PITCH 264  // bf16 elements per LDS row (256 + 8 pad), 528 B, 16B-aligned

typedef __attribute__((ext_vector_type(8))) short bf16x8;   // 8 bf16 = 4 VGPRs
typedef __attribute__((ext_vector_type(4))) float f32x4;    // MFMA 16x16 accum

// ---------- helpers ----------
__device__ __forceinline__ float bf2f(unsigned short u) {
  union { unsigned int i; float f; } v; v.i = ((unsigned int)u) << 16; return v.f;
}
__device__ __forceinline__ unsigned short f2bf(float f) {
  union { float f; unsigned int i; } v; v.f = f;
  unsigned int x = v.i;
  return (unsigned short)((x + 0x7fffu + ((x >> 16) & 1u)) >> 16);  // RNE
}
// split fp32 -> hi + lo bf16 (lo = rne(v - hi)), ~17 mantissa bits combined
__device__ __forceinline__ void fsplit(float v, unsigned short& hi, unsigned short& lo) {
  hi = f2bf(v);
  lo = f2bf(v - bf2f(hi));
}

// fp32 register-tiled GEMM core (precompute only): out[32][256] = sA[32][256] @ W.
__device__ __forceinline__ void gemm_tile(const float* __restrict__ sA,
                                          const float* __restrict__ W,
                                          int lane_j, int rg, float acc[8][4]) {
#pragma unroll
  for (int mm = 0; mm < 8; mm++)
#pragma unroll
    for (int cc = 0; cc < 4; cc++) acc[mm][cc] = 0.f;
  for (int k = 0; k < H; k += 4) {
    float tvf[8][4];
#pragma unroll
    for (int mm = 0; mm < 8; mm++)
      *(float4*)&tvf[mm][0] = *(const float4*)&sA[(rg * 8 + mm) * H + k];
#pragma unroll
    for (int kk = 0; kk < 4; kk++) {
      const float* wr = W + (k + kk) * H + lane_j;
      float w0 = wr[0], w1 = wr[64], w2 = wr[128], w3 = wr[192];
#pragma unroll
      for (int mm = 0; mm < 8; mm++) {
        float av = tvf[mm][kk];
        acc[mm][0] = fmaf(av, w0, acc[mm][0]);
        acc[mm][1] = fmaf(av, w1, acc[mm][1]);
        acc[mm][2] = fmaf(av, w2, acc[mm][2]);
        acc[mm][3] = fmaf(av, w3, acc[mm][3]);
      }
    }
  }
}

// ---------- precompute kernels ----------

__global__ void k_detect(const int* __restrict__ ei, int* __restrict__ flag) {
  if (threadIdx.x == 0 && blockIdx.x == 0)
    *flag = (ei[1] == 0 && ei[3] == 0 && ei[5] == 0 && ei[7] == 0) ? 1 : 0;
}

__global__ __launch_bounds__(256) void k_zero(float4* __restrict__ p, int n4) {
  int i = blockIdx.x * 256 + threadIdx.x;
  if (i < n4) p[i] = make_float4(0.f, 0.f, 0.f, 0.f);
}

__global__ __launch_bounds__(256) void k_node_proj(
    const float* __restrict__ x, const int* __restrict__ a,
    const float* __restrict__ w, const float* __restrict__ b,
    float* __restrict__ h, int N) {
  int node = blockIdx.x;
  int j = threadIdx.x;
  float acc = b[j];
  acc = fmaf(x[node * 3 + 0], w[0 * H + j], acc);
  acc = fmaf(x[node * 3 + 1], w[1 * H + j], acc);
  acc = fmaf(x[node * 3 + 2], w[2 * H + j], acc);
  acc = fmaf((float)a[node], w[3 * H + j], acc);
  h[(size_t)node * H + j] = fmaxf(acc, 0.f);
}

// WtC[l][j][k] = (em_w2 @ lin_w[l])[k][j], stored as hi/lo bf16 planes
__global__ __launch_bounds__(256, 2) void k_wcomb(
    const float* __restrict__ w2, const float* __restrict__ lin_w,
    unsigned short* __restrict__ wcTh, unsigned short* __restrict__ wcTl) {
  __shared__ __align__(16) float sA[32 * H];
  int l = blockIdx.x >> 3, tile = blockIdx.x & 7;
  int tid = threadIdx.x;
  const float4* src = (const float4*)(w2 + (size_t)tile * 32 * H);
#pragma unroll
  for (int it = 0; it < 8; it++) {
    int vi = it * 256 + tid;
    *(float4*)&sA[vi * 4] = src[vi];
  }
  __syncthreads();
  int lane_j = tid & 63, rg = tid >> 6;
  float acc[8][4];
  gemm_tile(sA, lin_w + (size_t)l * H * H, lane_j, rg, acc);
  unsigned short* oh = wcTh + (size_t)l * H * H;
  unsigned short* ol = wcTl + (size_t)l * H * H;
#pragma unroll
  for (int cc = 0; cc < 4; cc++) {
    int j = lane_j + 64 * cc;
#pragma unroll
    for (int mm = 0; mm < 8; mm++) {
      int k = tile * 32 + rg * 8 + mm;
      unsigned short hi, lo;
      fsplit(acc[mm][cc], hi, lo);
      oh[(size_t)j * H + k] = hi;  // transposed store
      ol[(size_t)j * H + k] = lo;
    }
  }
}

// beta[l] = em_b2 @ lin_w[l] + lin_b[l]
__global__ __launch_bounds__(256) void k_beta(
    const float* __restrict__ lin_w, const float* __restrict__ lin_b,
    const float* __restrict__ b2, float* __restrict__ beta) {
  int l = blockIdx.x, j = threadIdx.x;
  const float* W = lin_w + (size_t)l * H * H;
  float v = lin_b[l * H + j];
  for (int k = 0; k < H; k++) v = fmaf(b2[k], W[k * H + j], v);
  beta[l * H + j] = v;
}

// out_{h,l}[l][n][k] = bf16split(in[l][k][n])  (64x64 LDS-tiled transpose)
__global__ __launch_bounds__(256) void k_transp(
    const float* __restrict__ in,
    unsigned short* __restrict__ outh, unsigned short* __restrict__ outl) {
  int l = blockIdx.z;
  int kb = blockIdx.x * 64, nb = blockIdx.y * 64;
  int tid = threadIdx.x;
  __shared__ float T[64][65];
  const float* src = in + (size_t)l * H * H;
#pragma unroll
  for (int it = 0; it < 16; it++) {
    int idx = it * 256 + tid;
    int kl = idx >> 6, nl = idx & 63;
    T[kl][nl] = src[(size_t)(kb + kl) * H + nb + nl];
  }
  __syncthreads();
  unsigned short* dh = outh + (size_t)l * H * H;
  unsigned short* dl = outl + (size_t)l * H * H;
#pragma unroll
  for (int it = 0; it < 8; it++) {
    int u = it * 256 + tid;
    int nl = u >> 5, k2 = (u & 31) * 2;
    unsigned short h0, l0, h1, l1;
    fsplit(T[k2][nl], h0, l0);
    fsplit(T[k2 + 1][nl], h1, l1);
    size_t o = (size_t)(nb + nl) * H + kb + k2;
    *(unsigned int*)&dh[o] = (unsigned int)h0 | ((unsigned int)h1 << 16);
    *(unsigned int*)&dl[o] = (unsigned int)l0 | ((unsigned int)l1 << 16);
  }
}

// ---------- per-layer MFMA kernels ----------

// Edge: t = relu(ea@em_w1+em_b1) (split bf16, LDS); e_l = t @ WtC^T + beta
// (3-term split MFMA); msg = relu(h[src]+e_l); atomicAdd agg[dst].
// Tile = 64 edges x 256 cols.
__global__ __launch_bounds__(256) void k_edge_mfma(
    const float* __restrict__ ea,
    const float* __restrict__ w1, const float* __restrict__ b1,
    const unsigned short* __restrict__ Wth,  // [256 n][256 k] bf16 hi
    const unsigned short* __restrict__ Wtl,  // lo plane
    const float* __restrict__ beta,
    const float* __restrict__ h, float* __restrict__ agg,
    const void* __restrict__ ei, const int* __restrict__ flag64, int E) {
  __shared__ __align__(16) unsigned short sAh[64 * PITCH];
  __shared__ __align__(16) unsigned short sAl[64 * PITCH];
  __shared__ __align__(16) float sEA[64 * 4];
  __shared__ int sSrc[64];
  __shared__ int sDst[64];
  int tid = threadIdx.x;
  int base = blockIdx.x * 64;
  int is64 = *flag64;
  if (tid < 64) {
    long long v = is64 ? ((const long long*)ei)[base + tid]
                       : (long long)((const int*)ei)[base + tid];
    sSrc[tid] = (int)v;
  } else if (tid < 128) {
    int t = tid - 64;
    long long v = is64 ? ((const long long*)ei)[(size_t)E + base + t]
                       : (long long)((const int*)ei)[(size_t)E + base + t];
    sDst[t] = (int)v;
  } else if (tid < 192) {
    int t = tid - 128;
    ((float4*)sEA)[t] = ((const float4*)(ea + (size_t)base * 4))[t];
  }
  __syncthreads();
  {  // t-compute: thread -> col pair j2, 32 rows; store hi/lo planes
    int j2 = (tid & 127) * 2;
    int r0 = (tid >> 7) * 32;
    float wv0[4], wv1[4];
#pragma unroll
    for (int q = 0; q < 4; q++) { wv0[q] = w1[q * H + j2]; wv1[q] = w1[q * H + j2 + 1]; }
    float bb0 = b1[j2], bb1 = b1[j2 + 1];
    for (int m = r0; m < r0 + 32; m++) {
      float t0 = bb0, t1 = bb1;
#pragma unroll
      for (int q = 0; q < 4; q++) {
        float eav = sEA[m * 4 + q];
        t0 = fmaf(eav, wv0[q], t0);
        t1 = fmaf(eav, wv1[q], t1);
      }
      t0 = fmaxf(t0, 0.f); t1 = fmaxf(t1, 0.f);
      unsigned short h0, l0, h1, l1;
      fsplit(t0, h0, l0);
      fsplit(t1, h1, l1);
      *(unsigned int*)&sAh[m * PITCH + j2] = (unsigned int)h0 | ((unsigned int)h1 << 16);
      *(unsigned int*)&sAl[m * PITCH + j2] = (unsigned int)l0 | ((unsigned int)l1 << 16);
    }
  }
  __syncthreads();
  int lane = tid & 63, wv = tid >> 6;
  int lane15 = lane & 15, quad = lane >> 4;
  int rb0 = (wv & 1) * 32;    // this wave: rows rb0..rb0+15 and rb0+16..rb0+31
  int cg0 = (wv >> 1) * 8;    // col groups cg0..cg0+7 (16 cols each)
  f32x4 acc[2][8];
#pragma unroll
  for (int i = 0; i < 2; i++)
#pragma unroll
    for (int c = 0; c < 8; c++) acc[i][c] = (f32x4){0.f, 0.f, 0.f, 0.f};
  const unsigned short* a0h = sAh + (rb0 + lane15) * PITCH + quad * 8;
  const unsigned short* a0l = sAl + (rb0 + lane15) * PITCH + quad * 8;
  const unsigned short* bh = Wth + (size_t)(cg0 * 16 + lane15) * H + quad * 8;
  const unsigned short* bl = Wtl + (size_t)(cg0 * 16 + lane15) * H + quad * 8;
#pragma unroll
  for (int st = 0; st < 8; st++) {
    bf16x8 a0hf = *(const bf16x8*)(a0h + st * 32);
    bf16x8 a0lf = *(const bf16x8*)(a0l + st * 32);
    bf16x8 a1hf = *(const bf16x8*)(a0h + 16 * PITCH + st * 32);
    bf16x8 a1lf = *(const bf16x8*)(a0l + 16 * PITCH + st * 32);
#pragma unroll
    for (int cg = 0; cg < 8; cg++) {
      bf16x8 bhf = *(const bf16x8*)(bh + (size_t)cg * 16 * H + st * 32);
      bf16x8 blf = *(const bf16x8*)(bl + (size_t)cg * 16 * H + st * 32);
      acc[0][cg] = __builtin_amdgcn_mfma_f32_16x16x32_bf16(a0hf, bhf, acc[0][cg], 0, 0, 0);
      acc[0][cg] = __builtin_amdgcn_mfma_f32_16x16x32_bf16(a0lf, bhf, acc[0][cg], 0, 0, 0);
      acc[0][cg] = __builtin_amdgcn_mfma_f32_16x16x32_bf16(a0hf, blf, acc[0][cg], 0, 0, 0);
      acc[1][cg] = __builtin_amdgcn_mfma_f32_16x16x32_bf16(a1hf, bhf, acc[1][cg], 0, 0, 0);
      acc[1][cg] = __builtin_amdgcn_mfma_f32_16x16x32_bf16(a1lf, bhf, acc[1][cg], 0, 0, 0);
      acc[1][cg] = __builtin_amdgcn_mfma_f32_16x16x32_bf16(a1hf, blf, acc[1][cg], 0, 0, 0);
    }
  }
  float bv[8];
#pragma unroll
  for (int cg = 0; cg < 8; cg++) bv[cg] = beta[(cg0 + cg) * 16 + lane15];
#pragma unroll
  for (int rgi = 0; rgi < 2; rgi++) {
    int mb = rb0 + rgi * 16 + quad * 4;
#pragma unroll
    for (int r = 0; r < 4; r++) {
      int ml = mb + r;
      const float* hrow = h + (size_t)sSrc[ml] * H;
      float* arow = agg + (size_t)sDst[ml] * H;
#pragma unroll
      for (int cg = 0; cg < 8; cg++) {
        int j = (cg0 + cg) * 16 + lane15;
        float msg = fmaxf(hrow[j] + acc[rgi][cg][r] + bv[cg], 0.f);
        atomicAdd(&arow[j], msg);
      }
    }
  }
}

// Node: z=h+agg; z1=relu(z@w1+b1); z2=z1@w2+b2; LN; h += relu(LN).
// 3-term split MFMA. Tile = 64 nodes; wave w owns 16 rows x all 16 colgroups.
__global__ __launch_bounds__(256) void k_node_mfma(
    float* __restrict__ h, const float* __restrict__ agg,
    const unsigned short* __restrict__ w1Th, const unsigned short* __restrict__ w1Tl,
    const float* __restrict__ b1,
    const unsigned short* __restrict__ w2Th, const unsigned short* __restrict__ w2Tl,
    const float* __restrict__ b2,
    const float* __restrict__ lng, const float* __restrict__ lnb) {
  __shared__ __align__(16) unsigned short sAh[64 * PITCH];
  __shared__ __align__(16) unsigned short sAl[64 * PITCH];
  int tid = threadIdx.x;
  int base = blockIdx.x * 64;
  const float4* h4 = (const float4*)(h + (size_t)base * H);
  const float4* a4 = (const float4*)(agg + (size_t)base * H);
  // Stage ALL 64 rows: 64 rows x 64 float4/row = 4096 float4 -> 16 iterations.
  // (R3/R4 bug: 8 iterations staged only rows 0..31; rows 32..63 were stale LDS.)
#pragma unroll
  for (int it = 0; it < 16; it++) {
    int vi = it * 256 + tid;
    int row = vi >> 6, c4 = (vi & 63) * 4;
    float4 hv = h4[vi], av = a4[vi];
    float z[4] = {hv.x + av.x, hv.y + av.y, hv.z + av.z, hv.w + av.w};
    unsigned short hh[4], ll[4];
#pragma unroll
    for (int q = 0; q < 4; q++) fsplit(z[q], hh[q], ll[q]);
    uint2 uh, ul;
    uh.x = (unsigned int)hh[0] | ((unsigned int)hh[1] << 16);
    uh.y = (unsigned int)hh[2] | ((unsigned int)hh[3] << 16);
    ul.x = (unsigned int)ll[0] | ((unsigned int)ll[1] << 16);
    ul.y = (unsigned int)ll[2] | ((unsigned int)ll[3] << 16);
    *(uint2*)&sAh[row * PITCH + c4] = uh;
    *(uint2*)&sAl[row * PITCH + c4] = ul;
  }
  __syncthreads();
  int lane = tid & 63, wv = tid >> 6;
  int lane15 = lane & 15, quad = lane >> 4;
  const unsigned short* aph = sAh + (wv * 16 + lane15) * PITCH + quad * 8;
  const unsigned short* apl = sAl + (wv * 16 + lane15) * PITCH + quad * 8;
  f32x4 acc[16];
#pragma unroll
  for (int c = 0; c < 16; c++) acc[c] = (f32x4){0.f, 0.f, 0.f, 0.f};
  {
    const unsigned short* bph = w1Th + (size_t)lane15 * H + quad * 8;
    const unsigned short* bpl = w1Tl + (size_t)lane15 * H + quad * 8;
#pragma unroll
    for (int st = 0; st < 8; st++) {
      bf16x8 ahf = *(const bf16x8*)(aph + st * 32);
      bf16x8 alf = *(const bf16x8*)(apl + st * 32);
#pragma unroll
      for (int cg = 0; cg < 16; cg++) {
        bf16x8 bhf = *(const bf16x8*)(bph + (size_t)cg * 16 * H + st * 32);
        bf16x8 blf = *(const bf16x8*)(bpl + (size_t)cg * 16 * H + st * 32);
        acc[cg] = __builtin_amdgcn_mfma_f32_16x16x32_bf16(ahf, bhf, acc[cg], 0, 0, 0);
        acc[cg] = __builtin_amdgcn_mfma_f32_16x16x32_bf16(alf, bhf, acc[cg], 0, 0, 0);
        acc[cg] = __builtin_amdgcn_mfma_f32_16x16x32_bf16(ahf, blf, acc[cg], 0, 0, 0);
      }
    }
  }
  __syncthreads();  // all waves done reading sA (z)
#pragma unroll
  for (int cg = 0; cg < 16; cg++) {
    float bb = b1[cg * 16 + lane15];
#pragma unroll
    for (int r = 0; r < 4; r++) {
      int row = wv * 16 + quad * 4 + r;
      float z1 = fmaxf(acc[cg][r] + bb, 0.f);
      unsigned short hh, ll;
      fsplit(z1, hh, ll);
      sAh[row * PITCH + cg * 16 + lane15] = hh;
      sAl[row * PITCH + cg * 16 + lane15] = ll;
    }
  }
  __syncthreads();
  f32x4 acc2[16];
#pragma unroll
  for (int c = 0; c < 16; c++) acc2[c] = (f32x4){0.f, 0.f, 0.f, 0.f};
  {
    const unsigned short* bph = w2Th + (size_t)lane15 * H + quad * 8;
    const unsigned short* bpl = w2Tl + (size_t)lane15 * H + quad * 8;
#pragma unroll
    for (int st = 0; st < 8; st++) {
      bf16x8 ahf = *(const bf16x8*)(aph + st * 32);
      bf16x8 alf = *(const bf16x8*)(apl + st * 32);
#pragma unroll
      for (int cg = 0; cg < 16; cg++) {
        bf16x8 bhf = *(const bf16x8*)(bph + (size_t)cg * 16 * H + st * 32);
        bf16x8 blf = *(const bf16x8*)(bpl + (size_t)cg * 16 * H + st * 32);
        acc2[cg] = __builtin_amdgcn_mfma_f32_16x16x32_bf16(ahf, bhf, acc2[cg], 0, 0, 0);
        acc2[cg] = __builtin_amdgcn_mfma_f32_16x16x32_bf16(alf, bhf, acc2[cg], 0, 0, 0);
        acc2[cg] = __builtin_amdgcn_mfma_f32_16x16x32_bf16(ahf, blf, acc2[cg], 0, 0, 0);
      }
    }
  }
  float b2v[16], gv[16], bbv[16];
#pragma unroll
  for (int cg = 0; cg < 16; cg++) {
    int j = cg * 16 + lane15;
    b2v[cg] = b2[j]; gv[cg] = lng[j]; bbv[cg] = lnb[j];
  }
#pragma unroll
  for (int r = 0; r < 4; r++) {
    float z2[16];
    float s = 0.f, ss = 0.f;
#pragma unroll
    for (int cg = 0; cg < 16; cg++) {
      z2[cg] = acc2[cg][r] + b2v[cg];
      s += z2[cg];
      ss = fmaf(z2[cg], z2[cg], ss);
    }
    s += __shfl_xor(s, 1, 64); ss += __shfl_xor(ss, 1, 64);
    s += __shfl_xor(s, 2, 64); ss += __shfl_xor(ss, 2, 64);
    s += __shfl_xor(s, 4, 64); ss += __shfl_xor(ss, 4, 64);
    s += __shfl_xor(s, 8, 64); ss += __shfl_xor(ss, 8, 64);
    float mu = s * (1.f / H);
    float var = ss * (1.f / H) - mu * mu;
    float rstd = rsqrtf(var + LN_EPS);
    int row = base + wv * 16 + quad * 4 + r;
    float* hr = h + (size_t)row * H;
#pragma unroll
    for (int cg = 0; cg < 16; cg++) {
      int j = cg * 16 + lane15;
      float v = fmaf((z2[cg] - mu) * rstd, gv[cg], bbv[cg]);
      hr[j] = hr[j] + fmaxf(v, 0.f);
    }
  }
}

// Mean-pool per graph + head MLP. One block per graph.
__global__ __launch_bounds__(256) void k_pool_head(
    const float* __restrict__ h,
    const float* __restrict__ w1, const float* __restrict__ b1,
    const float* __restrict__ w2, const float* __restrict__ b2,
    float* __restrict__ out, int n) {
  __shared__ float sG[H];
  __shared__ float sT[H];
  __shared__ float sR[4];
  int b = blockIdx.x, tid = threadIdx.x;
  const float* hb = h + (size_t)b * n * H;
  float a0 = 0.f, a1 = 0.f, a2 = 0.f, a3 = 0.f;
  for (int i = 0; i < n; i += 4) {
    a0 += hb[(size_t)(i + 0) * H + tid];
    a1 += hb[(size_t)(i + 1) * H + tid];
    a2 += hb[(size_t)(i + 2) * H + tid];
    a3 += hb[(size_t)(i + 3) * H + tid];
  }
  sG[tid] = (a0 + a1 + a2 + a3) / (float)n;
  __syncthreads();
  float t = b1[tid];
  for (int k = 0; k < H; k++) t = fmaf(sG[k], w1[k * H + tid], t);
  sT[tid] = fmaxf(t, 0.f);
  __syncthreads();
  float p = sT[tid] * w2[tid];
#pragma unroll
  for (int off = 32; off > 0; off >>= 1) p += __shfl_xor(p, off, 64);
  if ((tid & 63) == 0) sR[tid >> 6] = p;
  __syncthreads();
  if (tid == 0) out[b] = sR[0] + sR[1] + sR[2] + sR[3] + b2[0];
}

// ---------- launcher ----------
extern "C" void kernel_launch(void* const* d_in, const int* in_sizes, int n_in,
                              void* d_out, int out_size, void* d_ws, size_t ws_size,
                              hipStream_t stream) {
  const float* x      = (const float*)d_in[0];
  const float* ea     = (const float*)d_in[1];
  const void*  ei     = d_in[2];
  const int*   a      = (const int*)d_in[3];
  const float* np_w   = (const float*)d_in[4];
  const float* np_b   = (const float*)d_in[5];
  const float* em_w1  = (const float*)d_in[6];
  const float* em_b1  = (const float*)d_in[7];
  const float* em_w2  = (const float*)d_in[8];
  const float* em_b2  = (const float*)d_in[9];
  const float* lin_w  = (const float*)d_in[10];
  const float* lin_b  = (const float*)d_in[11];
  const float* m_w1   = (const float*)d_in[12];
  const float* m_b1   = (const float*)d_in[13];
  const float* m_w2   = (const float*)d_in[14];
  const float* m_b2   = (const float*)d_in[15];
  const float* ln_g   = (const float*)d_in[16];
  const float* ln_b   = (const float*)d_in[17];
  const float* hd_w1  = (const float*)d_in[18];
  const float* hd_b1  = (const float*)d_in[19];
  const float* hd_w2  = (const float*)d_in[20];
  const float* hd_b2  = (const float*)d_in[21];

  int N = in_sizes[0] / 3;
  int E = in_sizes[1] / 4;
  int B = out_size;
  int n = N / B;

  // workspace layout (~69.5 MB)
  char* ws = (char*)d_ws;
  size_t off = 0;
  float* h    = (float*)(ws + off); off += (size_t)N * H * 4;
  float* agg  = (float*)(ws + off); off += (size_t)N * H * 4;
  unsigned short* wcTh = (unsigned short*)(ws + off); off += (size_t)3 * H * H * 2;
  unsigned short* wcTl = (unsigned short*)(ws + off); off += (size_t)3 * H * H * 2;
  unsigned short* w1Th = (unsigned short*)(ws + off); off += (size_t)3 * H * H * 2;
  unsigned short* w1Tl = (unsigned short*)(ws + off); off += (size_t)3 * H * H * 2;
  unsigned short* w2Th = (unsigned short*)(ws + off); off += (size_t)3 * H * H * 2;
  unsigned short* w2Tl = (unsigned short*)(ws + off); off += (size_t)3 * H * H * 2;
  float* beta = (float*)(ws + off); off += 3 * H * 4;
  int* flag   = (int*)(ws + off);

  float* out = (float*)d_out;

  k_detect<<<1, 64, 0, stream>>>((const int*)ei, flag);
  k_node_proj<<<N, 256, 0, stream>>>(x, a, np_w, np_b, h, N);
  k_wcomb<<<24, 256, 0, stream>>>(em_w2, lin_w, wcTh, wcTl);
  k_beta<<<3, 256, 0, stream>>>(lin_w, lin_b, em_b2, beta);
  k_transp<<<dim3(4, 4, 3), 256, 0, stream>>>(m_w1, w1Th, w1Tl);
  k_transp<<<dim3(4, 4, 3), 256, 0, stream>>>(m_w2, w2Th, w2Tl);

  int n4 = N * H / 4;
  for (int l = 0; l < 3; l++) {
    k_zero<<<(n4 + 255) / 256, 256, 0, stream>>>((float4*)agg, n4);
    k_edge_mfma<<<E / 64, 256, 0, stream>>>(ea, em_w1, em_b1,
                                            wcTh + (size_t)l * H * H,
                                            wcTl + (size_t)l * H * H,
                                            beta + (size_t)l * H,
                                            h, agg, ei, flag, E);
    k_node_mfma<<<N / 64, 256, 0, stream>>>(h, agg,
                                            w1Th + (size_t)l * H * H,
                                            w1Tl + (size_t)l * H * H,
                                            m_b1 + (size_t)l * H,
                                            w2Th + (size_t)l * H * H,
                                            w2Tl + (size_t)l * H * H,
                                            m_b2 + (size_t)l * H,
                                            ln_g + (size_t)l * H, ln_b + (size_t)l * H);
  }
  k_pool_head<<<B, 256, 0, stream>>>(h, hd_w1, hd_b1, hd_w2, hd_b2, out, n);
}

// Round 6
// 2585.546 us; speedup vs baseline: 1.3601x; 1.2253x over previous
//
#include <hip/hip_runtime.h>
#include <hip/hip_bf16.h>

#define H 256
#define LN_EPS 1e-5f
#define PITCH 264   // bf16 elements per LDS A-row (256 + 8 pad), 528 B
#define ELP 260     // f32 elements per LDS el-row (256 + 4 pad)

typedef __attribute__((ext_vector_type(8))) short bf16x8;   // 8 bf16 = 4 VGPRs
typedef __attribute__((ext_vector_type(4))) float f32x4;    // MFMA 16x16 accum

// ---------- helpers ----------
__device__ __forceinline__ float bf2f(unsigned short u) {
  union { unsigned int i; float f; } v; v.i = ((unsigned int)u) << 16; return v.f;
}
__device__ __forceinline__ unsigned short f2bf(float f) {
  union { float f; unsigned int i; } v; v.f = f;
  unsigned int x = v.i;
  return (unsigned short)((x + 0x7fffu + ((x >> 16) & 1u)) >> 16);  // RNE
}
__device__ __forceinline__ void fsplit(float v, unsigned short& hi, unsigned short& lo) {
  hi = f2bf(v);
  lo = f2bf(v - bf2f(hi));
}

// fp32 register-tiled GEMM core (precompute only)
__device__ __forceinline__ void gemm_tile(const float* __restrict__ sA,
                                          const float* __restrict__ W,
                                          int lane_j, int rg, float acc[8][4]) {
#pragma unroll
  for (int mm = 0; mm < 8; mm++)
#pragma unroll
    for (int cc = 0; cc < 4; cc++) acc[mm][cc] = 0.f;
  for (int k = 0; k < H; k += 4) {
    float tvf[8][4];
#pragma unroll
    for (int mm = 0; mm < 8; mm++)
      *(float4*)&tvf[mm][0] = *(const float4*)&sA[(rg * 8 + mm) * H + k];
#pragma unroll
    for (int kk = 0; kk < 4; kk++) {
      const float* wr = W + (k + kk) * H + lane_j;
      float w0 = wr[0], w1 = wr[64], w2 = wr[128], w3 = wr[192];
#pragma unroll
      for (int mm = 0; mm < 8; mm++) {
        float av = tvf[mm][kk];
        acc[mm][0] = fmaf(av, w0, acc[mm][0]);
        acc[mm][1] = fmaf(av, w1, acc[mm][1]);
        acc[mm][2] = fmaf(av, w2, acc[mm][2]);
        acc[mm][3] = fmaf(av, w3, acc[mm][3]);
      }
    }
  }
}

// ---------- precompute kernels ----------

__global__ void k_detect(const int* __restrict__ ei, int* __restrict__ flag) {
  if (threadIdx.x == 0 && blockIdx.x == 0)
    *flag = (ei[1] == 0 && ei[3] == 0 && ei[5] == 0 && ei[7] == 0) ? 1 : 0;
}

__global__ __launch_bounds__(256) void k_zero(float4* __restrict__ p, int n4) {
  int i = blockIdx.x * 256 + threadIdx.x;
  if (i < n4) p[i] = make_float4(0.f, 0.f, 0.f, 0.f);
}

// dst histogram
__global__ __launch_bounds__(256) void k_hist(
    const void* __restrict__ ei, const int* __restrict__ flag64,
    int* __restrict__ hist, int E) {
  int e = blockIdx.x * 256 + threadIdx.x;
  if (e >= E) return;
  int d = (*flag64) ? (int)((const long long*)ei)[(size_t)E + e]
                    : ((const int*)ei)[(size_t)E + e];
  atomicAdd(&hist[d], 1);
}

// exclusive prefix sum over hist[N] -> cursor[N] (single block, 256 threads)
__global__ __launch_bounds__(256) void k_scan(
    const int* __restrict__ hist, int* __restrict__ cursor, int N) {
  __shared__ int part[256];
  int tid = threadIdx.x;
  int chunk = (N + 255) / 256;
  int s = 0;
  for (int i = 0; i < chunk; i++) {
    int idx = tid * chunk + i;
    if (idx < N) s += hist[idx];
  }
  part[tid] = s;
  __syncthreads();
  for (int off = 1; off < 256; off <<= 1) {
    int v = (tid >= off) ? part[tid - off] : 0;
    __syncthreads();
    part[tid] += v;
    __syncthreads();
  }
  int excl = (tid == 0) ? 0 : part[tid - 1];
  for (int i = 0; i < chunk; i++) {
    int idx = tid * chunk + i;
    if (idx < N) {
      cursor[idx] = excl;
      excl += hist[idx];
    }
  }
}

// scatter edges into dst-sorted order (src, dst, edge_attr)
__global__ __launch_bounds__(256) void k_scatter(
    const void* __restrict__ ei, const int* __restrict__ flag64,
    const float* __restrict__ ea, int* __restrict__ cursor,
    int* __restrict__ srcS, int* __restrict__ dstS, float* __restrict__ eaS, int E) {
  int e = blockIdx.x * 256 + threadIdx.x;
  if (e >= E) return;
  int is64 = *flag64;
  int s = is64 ? (int)((const long long*)ei)[e] : ((const int*)ei)[e];
  int d = is64 ? (int)((const long long*)ei)[(size_t)E + e]
               : ((const int*)ei)[(size_t)E + e];
  int p = atomicAdd(&cursor[d], 1);
  srcS[p] = s;
  dstS[p] = d;
  ((float4*)eaS)[p] = ((const float4*)ea)[e];
}

__global__ __launch_bounds__(256) void k_node_proj(
    const float* __restrict__ x, const int* __restrict__ a,
    const float* __restrict__ w, const float* __restrict__ b,
    float* __restrict__ h, int N) {
  int node = blockIdx.x;
  int j = threadIdx.x;
  float acc = b[j];
  acc = fmaf(x[node * 3 + 0], w[0 * H + j], acc);
  acc = fmaf(x[node * 3 + 1], w[1 * H + j], acc);
  acc = fmaf(x[node * 3 + 2], w[2 * H + j], acc);
  acc = fmaf((float)a[node], w[3 * H + j], acc);
  h[(size_t)node * H + j] = fmaxf(acc, 0.f);
}

// WtC[l][j][k] = (em_w2 @ lin_w[l])[k][j], hi/lo bf16 planes
__global__ __launch_bounds__(256, 2) void k_wcomb(
    const float* __restrict__ w2, const float* __restrict__ lin_w,
    unsigned short* __restrict__ wcTh, unsigned short* __restrict__ wcTl) {
  __shared__ __align__(16) float sA[32 * H];
  int l = blockIdx.x >> 3, tile = blockIdx.x & 7;
  int tid = threadIdx.x;
  const float4* src = (const float4*)(w2 + (size_t)tile * 32 * H);
#pragma unroll
  for (int it = 0; it < 8; it++) {
    int vi = it * 256 + tid;
    *(float4*)&sA[vi * 4] = src[vi];
  }
  __syncthreads();
  int lane_j = tid & 63, rg = tid >> 6;
  float acc[8][4];
  gemm_tile(sA, lin_w + (size_t)l * H * H, lane_j, rg, acc);
  unsigned short* oh = wcTh + (size_t)l * H * H;
  unsigned short* ol = wcTl + (size_t)l * H * H;
#pragma unroll
  for (int cc = 0; cc < 4; cc++) {
    int j = lane_j + 64 * cc;
#pragma unroll
    for (int mm = 0; mm < 8; mm++) {
      int k = tile * 32 + rg * 8 + mm;
      unsigned short hi, lo;
      fsplit(acc[mm][cc], hi, lo);
      oh[(size_t)j * H + k] = hi;
      ol[(size_t)j * H + k] = lo;
    }
  }
}

// beta[l] = em_b2 @ lin_w[l] + lin_b[l]
__global__ __launch_bounds__(256) void k_beta(
    const float* __restrict__ lin_w, const float* __restrict__ lin_b,
    const float* __restrict__ b2, float* __restrict__ beta) {
  int l = blockIdx.x, j = threadIdx.x;
  const float* W = lin_w + (size_t)l * H * H;
  float v = lin_b[l * H + j];
  for (int k = 0; k < H; k++) v = fmaf(b2[k], W[k * H + j], v);
  beta[l * H + j] = v;
}

// out_{h,l}[l][n][k] = bf16split(in[l][k][n])
__global__ __launch_bounds__(256) void k_transp(
    const float* __restrict__ in,
    unsigned short* __restrict__ outh, unsigned short* __restrict__ outl) {
  int l = blockIdx.z;
  int kb = blockIdx.x * 64, nb = blockIdx.y * 64;
  int tid = threadIdx.x;
  __shared__ float T[64][65];
  const float* src = in + (size_t)l * H * H;
#pragma unroll
  for (int it = 0; it < 16; it++) {
    int idx = it * 256 + tid;
    int kl = idx >> 6, nl = idx & 63;
    T[kl][nl] = src[(size_t)(kb + kl) * H + nb + nl];
  }
  __syncthreads();
  unsigned short* dh = outh + (size_t)l * H * H;
  unsigned short* dl = outl + (size_t)l * H * H;
#pragma unroll
  for (int it = 0; it < 8; it++) {
    int u = it * 256 + tid;
    int nl = u >> 5, k2 = (u & 31) * 2;
    unsigned short h0, l0, h1, l1;
    fsplit(T[k2][nl], h0, l0);
    fsplit(T[k2 + 1][nl], h1, l1);
    size_t o = (size_t)(nb + nl) * H + kb + k2;
    *(unsigned int*)&dh[o] = (unsigned int)h0 | ((unsigned int)h1 << 16);
    *(unsigned int*)&dl[o] = (unsigned int)l0 | ((unsigned int)l1 << 16);
  }
}

// ---------- per-layer MFMA kernels ----------

// Edge (dst-sorted): t = relu(eaS@em_w1+em_b1); e_l = t@WtC^T + beta (split MFMA);
// el -> LDS; segment-reduced scatter: thread j walks 64 sorted rows of col j,
// one atomicAdd per distinct dst. Tile = 64 edges x 256 cols.
__global__ __launch_bounds__(256) void k_edge_mfma(
    const float* __restrict__ eaS,
    const float* __restrict__ w1, const float* __restrict__ b1,
    const unsigned short* __restrict__ Wth, const unsigned short* __restrict__ Wtl,
    const float* __restrict__ beta,
    const float* __restrict__ h, float* __restrict__ agg,
    const int* __restrict__ srcS, const int* __restrict__ dstS) {
  __shared__ __align__(16) char smem[64 * PITCH * 2 * 2];  // 67.6 KB, aliased
  unsigned short* sAh = (unsigned short*)smem;
  unsigned short* sAl = sAh + 64 * PITCH;
  float* elbuf = (float*)smem;                             // reused after MFMA
  __shared__ __align__(16) float sEA[64 * 4];
  __shared__ int sSrc[64];
  __shared__ int sDst[64];
  int tid = threadIdx.x;
  int base = blockIdx.x * 64;
  if (tid < 64) {
    sSrc[tid] = srcS[base + tid];
  } else if (tid < 128) {
    sDst[tid - 64] = dstS[base + tid - 64];
  } else if (tid < 192) {
    int t = tid - 128;
    ((float4*)sEA)[t] = ((const float4*)(eaS + (size_t)base * 4))[t];
  }
  __syncthreads();
  {  // t = relu(eaS @ w1 + b1) -> split bf16 LDS
    int j2 = (tid & 127) * 2;
    int r0 = (tid >> 7) * 32;
    float wv0[4], wv1[4];
#pragma unroll
    for (int q = 0; q < 4; q++) { wv0[q] = w1[q * H + j2]; wv1[q] = w1[q * H + j2 + 1]; }
    float bb0 = b1[j2], bb1 = b1[j2 + 1];
    for (int m = r0; m < r0 + 32; m++) {
      float t0 = bb0, t1 = bb1;
#pragma unroll
      for (int q = 0; q < 4; q++) {
        float eav = sEA[m * 4 + q];
        t0 = fmaf(eav, wv0[q], t0);
        t1 = fmaf(eav, wv1[q], t1);
      }
      t0 = fmaxf(t0, 0.f); t1 = fmaxf(t1, 0.f);
      unsigned short h0, l0, h1, l1;
      fsplit(t0, h0, l0);
      fsplit(t1, h1, l1);
      *(unsigned int*)&sAh[m * PITCH + j2] = (unsigned int)h0 | ((unsigned int)h1 << 16);
      *(unsigned int*)&sAl[m * PITCH + j2] = (unsigned int)l0 | ((unsigned int)l1 << 16);
    }
  }
  __syncthreads();
  int lane = tid & 63, wv = tid >> 6;
  int lane15 = lane & 15, quad = lane >> 4;
  int rb0 = (wv & 1) * 32;
  int cg0 = (wv >> 1) * 8;
  f32x4 acc[2][8];
#pragma unroll
  for (int i = 0; i < 2; i++)
#pragma unroll
    for (int c = 0; c < 8; c++) acc[i][c] = (f32x4){0.f, 0.f, 0.f, 0.f};
  const unsigned short* a0h = sAh + (rb0 + lane15) * PITCH + quad * 8;
  const unsigned short* a0l = sAl + (rb0 + lane15) * PITCH + quad * 8;
  const unsigned short* bh = Wth + (size_t)(cg0 * 16 + lane15) * H + quad * 8;
  const unsigned short* bl = Wtl + (size_t)(cg0 * 16 + lane15) * H + quad * 8;
#pragma unroll
  for (int st = 0; st < 8; st++) {
    bf16x8 a0hf = *(const bf16x8*)(a0h + st * 32);
    bf16x8 a0lf = *(const bf16x8*)(a0l + st * 32);
    bf16x8 a1hf = *(const bf16x8*)(a0h + 16 * PITCH + st * 32);
    bf16x8 a1lf = *(const bf16x8*)(a0l + 16 * PITCH + st * 32);
#pragma unroll
    for (int cg = 0; cg < 8; cg++) {
      bf16x8 bhf = *(const bf16x8*)(bh + (size_t)cg * 16 * H + st * 32);
      bf16x8 blf = *(const bf16x8*)(bl + (size_t)cg * 16 * H + st * 32);
      acc[0][cg] = __builtin_amdgcn_mfma_f32_16x16x32_bf16(a0hf, bhf, acc[0][cg], 0, 0, 0);
      acc[0][cg] = __builtin_amdgcn_mfma_f32_16x16x32_bf16(a0lf, bhf, acc[0][cg], 0, 0, 0);
      acc[0][cg] = __builtin_amdgcn_mfma_f32_16x16x32_bf16(a0hf, blf, acc[0][cg], 0, 0, 0);
      acc[1][cg] = __builtin_amdgcn_mfma_f32_16x16x32_bf16(a1hf, bhf, acc[1][cg], 0, 0, 0);
      acc[1][cg] = __builtin_amdgcn_mfma_f32_16x16x32_bf16(a1lf, bhf, acc[1][cg], 0, 0, 0);
      acc[1][cg] = __builtin_amdgcn_mfma_f32_16x16x32_bf16(a1hf, blf, acc[1][cg], 0, 0, 0);
    }
  }
  float bv[8];
#pragma unroll
  for (int cg = 0; cg < 8; cg++) bv[cg] = beta[(cg0 + cg) * 16 + lane15];
  __syncthreads();  // all waves done reading sAh/sAl; smem becomes elbuf
#pragma unroll
  for (int rgi = 0; rgi < 2; rgi++) {
#pragma unroll
    for (int r = 0; r < 4; r++) {
      int row = rb0 + rgi * 16 + quad * 4 + r;
#pragma unroll
      for (int cg = 0; cg < 8; cg++) {
        int j = (cg0 + cg) * 16 + lane15;
        elbuf[row * ELP + j] = acc[rgi][cg][r] + bv[cg];
      }
    }
  }
  __syncthreads();
  // segment-reduced scatter: thread j handles column j over 64 dst-sorted rows.
  // dst-transition branch is block-uniform (same m-sequence for all threads).
  {
    int j = tid;
    float run = 0.f;
    int prev = sDst[0];
    for (int m0 = 0; m0 < 64; m0 += 8) {
      float hv[8];
#pragma unroll
      for (int q = 0; q < 8; q++)
        hv[q] = h[(size_t)sSrc[m0 + q] * H + j];  // 8 independent gathers in flight
#pragma unroll
      for (int q = 0; q < 8; q++) {
        int m = m0 + q;
        int d = sDst[m];
        float msg = fmaxf(hv[q] + elbuf[m * ELP + j], 0.f);
        if (d != prev) {
          atomicAdd(&agg[(size_t)prev * H + j], run);
          run = 0.f;
          prev = d;
        }
        run += msg;
      }
    }
    atomicAdd(&agg[(size_t)prev * H + j], run);
  }
}

// Node: z=h+agg; z1=relu(z@w1+b1); z2=z1@w2+b2; LN; h += relu(LN).
__global__ __launch_bounds__(256) void k_node_mfma(
    float* __restrict__ h, const float* __restrict__ agg,
    const unsigned short* __restrict__ w1Th, const unsigned short* __restrict__ w1Tl,
    const float* __restrict__ b1,
    const unsigned short* __restrict__ w2Th, const unsigned short* __restrict__ w2Tl,
    const float* __restrict__ b2,
    const float* __restrict__ lng, const float* __restrict__ lnb) {
  __shared__ __align__(16) unsigned short sAh[64 * PITCH];
  __shared__ __align__(16) unsigned short sAl[64 * PITCH];
  int tid = threadIdx.x;
  int base = blockIdx.x * 64;
  const float4* h4 = (const float4*)(h + (size_t)base * H);
  const float4* a4 = (const float4*)(agg + (size_t)base * H);
#pragma unroll
  for (int it = 0; it < 16; it++) {  // all 64 rows (4096 float4)
    int vi = it * 256 + tid;
    int row = vi >> 6, c4 = (vi & 63) * 4;
    float4 hv = h4[vi], av = a4[vi];
    float z[4] = {hv.x + av.x, hv.y + av.y, hv.z + av.z, hv.w + av.w};
    unsigned short hh[4], ll[4];
#pragma unroll
    for (int q = 0; q < 4; q++) fsplit(z[q], hh[q], ll[q]);
    uint2 uh, ul;
    uh.x = (unsigned int)hh[0] | ((unsigned int)hh[1] << 16);
    uh.y = (unsigned int)hh[2] | ((unsigned int)hh[3] << 16);
    ul.x = (unsigned int)ll[0] | ((unsigned int)ll[1] << 16);
    ul.y = (unsigned int)ll[2] | ((unsigned int)ll[3] << 16);
    *(uint2*)&sAh[row * PITCH + c4] = uh;
    *(uint2*)&sAl[row * PITCH + c4] = ul;
  }
  __syncthreads();
  int lane = tid & 63, wv = tid >> 6;
  int lane15 = lane & 15, quad = lane >> 4;
  const unsigned short* aph = sAh + (wv * 16 + lane15) * PITCH + quad * 8;
  const unsigned short* apl = sAl + (wv * 16 + lane15) * PITCH + quad * 8;
  f32x4 acc[16];
#pragma unroll
  for (int c = 0; c < 16; c++) acc[c] = (f32x4){0.f, 0.f, 0.f, 0.f};
  {
    const unsigned short* bph = w1Th + (size_t)lane15 * H + quad * 8;
    const unsigned short* bpl = w1Tl + (size_t)lane15 * H + quad * 8;
#pragma unroll
    for (int st = 0; st < 8; st++) {
      bf16x8 ahf = *(const bf16x8*)(aph + st * 32);
      bf16x8 alf = *(const bf16x8*)(apl + st * 32);
#pragma unroll
      for (int cg = 0; cg < 16; cg++) {
        bf16x8 bhf = *(const bf16x8*)(bph + (size_t)cg * 16 * H + st * 32);
        bf16x8 blf = *(const bf16x8*)(bpl + (size_t)cg * 16 * H + st * 32);
        acc[cg] = __builtin_amdgcn_mfma_f32_16x16x32_bf16(ahf, bhf, acc[cg], 0, 0, 0);
        acc[cg] = __builtin_amdgcn_mfma_f32_16x16x32_bf16(alf, bhf, acc[cg], 0, 0, 0);
        acc[cg] = __builtin_amdgcn_mfma_f32_16x16x32_bf16(ahf, blf, acc[cg], 0, 0, 0);
      }
    }
  }
  __syncthreads();
#pragma unroll
  for (int cg = 0; cg < 16; cg++) {
    float bb = b1[cg * 16 + lane15];
#pragma unroll
    for (int r = 0; r < 4; r++) {
      int row = wv * 16 + quad * 4 + r;
      float z1 = fmaxf(acc[cg][r] + bb, 0.f);
      unsigned short hh, ll;
      fsplit(z1, hh, ll);
      sAh[row * PITCH + cg * 16 + lane15] = hh;
      sAl[row * PITCH + cg * 16 + lane15] = ll;
    }
  }
  __syncthreads();
  f32x4 acc2[16];
#pragma unroll
  for (int c = 0; c < 16; c++) acc2[c] = (f32x4){0.f, 0.f, 0.f, 0.f};
  {
    const unsigned short* bph = w2Th + (size_t)lane15 * H + quad * 8;
    const unsigned short* bpl = w2Tl + (size_t)lane15 * H + quad * 8;
#pragma unroll
    for (int st = 0; st < 8; st++) {
      bf16x8 ahf = *(const bf16x8*)(aph + st * 32);
      bf16x8 alf = *(const bf16x8*)(apl + st * 32);
#pragma unroll
      for (int cg = 0; cg < 16; cg++) {
        bf16x8 bhf = *(const bf16x8*)(bph + (size_t)cg * 16 * H + st * 32);
        bf16x8 blf = *(const bf16x8*)(bpl + (size_t)cg * 16 * H + st * 32);
        acc2[cg] = __builtin_amdgcn_mfma_f32_16x16x32_bf16(ahf, bhf, acc2[cg], 0, 0, 0);
        acc2[cg] = __builtin_amdgcn_mfma_f32_16x16x32_bf16(alf, bhf, acc2[cg], 0, 0, 0);
        acc2[cg] = __builtin_amdgcn_mfma_f32_16x16x32_bf16(ahf, blf, acc2[cg], 0, 0, 0);
      }
    }
  }
  float b2v[16], gv[16], bbv[16];
#pragma unroll
  for (int cg = 0; cg < 16; cg++) {
    int j = cg * 16 + lane15;
    b2v[cg] = b2[j]; gv[cg] = lng[j]; bbv[cg] = lnb[j];
  }
#pragma unroll
  for (int r = 0; r < 4; r++) {
    float z2[16];
    float s = 0.f, ss = 0.f;
#pragma unroll
    for (int cg = 0; cg < 16; cg++) {
      z2[cg] = acc2[cg][r] + b2v[cg];
      s += z2[cg];
      ss = fmaf(z2[cg], z2[cg], ss);
    }
    s += __shfl_xor(s, 1, 64); ss += __shfl_xor(ss, 1, 64);
    s += __shfl_xor(s, 2, 64); ss += __shfl_xor(ss, 2, 64);
    s += __shfl_xor(s, 4, 64); ss += __shfl_xor(ss, 4, 64);
    s += __shfl_xor(s, 8, 64); ss += __shfl_xor(ss, 8, 64);
    float mu = s * (1.f / H);
    float var = ss * (1.f / H) - mu * mu;
    float rstd = rsqrtf(var + LN_EPS);
    int row = base + wv * 16 + quad * 4 + r;
    float* hr = h + (size_t)row * H;
#pragma unroll
    for (int cg = 0; cg < 16; cg++) {
      int j = cg * 16 + lane15;
      float v = fmaf((z2[cg] - mu) * rstd, gv[cg], bbv[cg]);
      hr[j] = hr[j] + fmaxf(v, 0.f);
    }
  }
}

// Mean-pool per graph + head MLP. One block per graph.
__global__ __launch_bounds__(256) void k_pool_head(
    const float* __restrict__ h,
    const float* __restrict__ w1, const float* __restrict__ b1,
    const float* __restrict__ w2, const float* __restrict__ b2,
    float* __restrict__ out, int n) {
  __shared__ float sG[H];
  __shared__ float sT[H];
  __shared__ float sR[4];
  int b = blockIdx.x, tid = threadIdx.x;
  const float* hb = h + (size_t)b * n * H;
  float a0 = 0.f, a1 = 0.f, a2 = 0.f, a3 = 0.f;
  for (int i = 0; i < n; i += 4) {
    a0 += hb[(size_t)(i + 0) * H + tid];
    a1 += hb[(size_t)(i + 1) * H + tid];
    a2 += hb[(size_t)(i + 2) * H + tid];
    a3 += hb[(size_t)(i + 3) * H + tid];
  }
  sG[tid] = (a0 + a1 + a2 + a3) / (float)n;
  __syncthreads();
  float t = b1[tid];
  for (int k = 0; k < H; k++) t = fmaf(sG[k], w1[k * H + tid], t);
  sT[tid] = fmaxf(t, 0.f);
  __syncthreads();
  float p = sT[tid] * w2[tid];
#pragma unroll
  for (int off = 32; off > 0; off >>= 1) p += __shfl_xor(p, off, 64);
  if ((tid & 63) == 0) sR[tid >> 6] = p;
  __syncthreads();
  if (tid == 0) out[b] = sR[0] + sR[1] + sR[2] + sR[3] + b2[0];
}

// ---------- launcher ----------
extern "C" void kernel_launch(void* const* d_in, const int* in_sizes, int n_in,
                              void* d_out, int out_size, void* d_ws, size_t ws_size,
                              hipStream_t stream) {
  const float* x      = (const float*)d_in[0];
  const float* ea     = (const float*)d_in[1];
  const void*  ei     = d_in[2];
  const int*   a      = (const int*)d_in[3];
  const float* np_w   = (const float*)d_in[4];
  const float* np_b   = (const float*)d_in[5];
  const float* em_w1  = (const float*)d_in[6];
  const float* em_b1  = (const float*)d_in[7];
  const float* em_w2  = (const float*)d_in[8];
  const float* em_b2  = (const float*)d_in[9];
  const float* lin_w  = (const float*)d_in[10];
  const float* lin_b  = (const float*)d_in[11];
  const float* m_w1   = (const float*)d_in[12];
  const float* m_b1   = (const float*)d_in[13];
  const float* m_w2   = (const float*)d_in[14];
  const float* m_b2   = (const float*)d_in[15];
  const float* ln_g   = (const float*)d_in[16];
  const float* ln_b   = (const float*)d_in[17];
  const float* hd_w1  = (const float*)d_in[18];
  const float* hd_b1  = (const float*)d_in[19];
  const float* hd_w2  = (const float*)d_in[20];
  const float* hd_b2  = (const float*)d_in[21];

  int N = in_sizes[0] / 3;
  int E = in_sizes[1] / 4;
  int B = out_size;
  int n = N / B;

  // workspace layout (~82 MB)
  char* ws = (char*)d_ws;
  size_t off = 0;
  auto alloc = [&](size_t bytes) {
    char* p = ws + off;
    off += (bytes + 255) & ~(size_t)255;
    return p;
  };
  float* h    = (float*)alloc((size_t)N * H * 4);
  float* agg  = (float*)alloc((size_t)N * H * 4);
  unsigned short* wcTh = (unsigned short*)alloc((size_t)3 * H * H * 2);
  unsigned short* wcTl = (unsigned short*)alloc((size_t)3 * H * H * 2);
  unsigned short* w1Th = (unsigned short*)alloc((size_t)3 * H * H * 2);
  unsigned short* w1Tl = (unsigned short*)alloc((size_t)3 * H * H * 2);
  unsigned short* w2Th = (unsigned short*)alloc((size_t)3 * H * H * 2);
  unsigned short* w2Tl = (unsigned short*)alloc((size_t)3 * H * H * 2);
  float* beta  = (float*)alloc(3 * H * 4);
  int*   flag  = (int*)alloc(4);
  int*   hist  = (int*)alloc((size_t)N * 4);
  int*   curs  = (int*)alloc((size_t)N * 4);
  int*   srcS  = (int*)alloc((size_t)E * 4);
  int*   dstS  = (int*)alloc((size_t)E * 4);
  float* eaS   = (float*)alloc((size_t)E * 4 * 4);

  float* out = (float*)d_out;
  int ebl = (E + 255) / 256;

  k_detect<<<1, 64, 0, stream>>>((const int*)ei, flag);
  k_zero<<<(N + 1023) / 1024, 256, 0, stream>>>((float4*)hist, N / 4);
  k_hist<<<ebl, 256, 0, stream>>>(ei, flag, hist, E);
  k_scan<<<1, 256, 0, stream>>>(hist, curs, N);
  k_scatter<<<ebl, 256, 0, stream>>>(ei, flag, ea, curs, srcS, dstS, eaS, E);
  k_node_proj<<<N, 256, 0, stream>>>(x, a, np_w, np_b, h, N);
  k_wcomb<<<24, 256, 0, stream>>>(em_w2, lin_w, wcTh, wcTl);
  k_beta<<<3, 256, 0, stream>>>(lin_w, lin_b, em_b2, beta);
  k_transp<<<dim3(4, 4, 3), 256, 0, stream>>>(m_w1, w1Th, w1Tl);
  k_transp<<<dim3(4, 4, 3), 256, 0, stream>>>(m_w2, w2Th, w2Tl);

  int n4 = N * H / 4;
  for (int l = 0; l < 3; l++) {
    k_zero<<<(n4 + 255) / 256, 256, 0, stream>>>((float4*)agg, n4);
    k_edge_mfma<<<E / 64, 256, 0, stream>>>(eaS, em_w1, em_b1,
                                            wcTh + (size_t)l * H * H,
                                            wcTl + (size_t)l * H * H,
                                            beta + (size_t)l * H,
                                            h, agg, srcS, dstS);
    k_node_mfma<<<N / 64, 256, 0, stream>>>(h, agg,
                                            w1Th + (size_t)l * H * H,
                                            w1Tl + (size_t)l * H * H,
                                            m_b1 + (size_t)l * H,
                                            w2Th + (size_t)l * H * H,
                                            w2Tl + (size_t)l * H * H,
                                            m_b2 + (size_t)l * H,
                                            ln_g + (size_t)l * H, ln_b + (size_t)l * H);
  }
  k_pool_head<<<B, 256, 0, stream>>>(h, hd_w1, hd_b1, hd_w2, hd_b2, out, n);
}

// Round 8
// 2330.805 us; speedup vs baseline: 1.5088x; 1.1093x over previous
//
#include <hip/hip_runtime.h>
#include <hip/hip_bf16.h>

#define H 256
#define LN_EPS 1e-5f
#define PITCH 264   // bf16 elements per LDS A-row (256 + 8 pad), 528 B
#define ELP 260     // f32 elements per LDS el-row (256 + 4 pad)
#define TE 32       // edges per tile (edge kernel)

typedef __attribute__((ext_vector_type(8))) short bf16x8;   // 8 bf16 = 4 VGPRs
typedef __attribute__((ext_vector_type(4))) float f32x4;    // MFMA 16x16 accum

// ---------- helpers ----------
__device__ __forceinline__ float bf2f(unsigned short u) {
  union { unsigned int i; float f; } v; v.i = ((unsigned int)u) << 16; return v.f;
}
__device__ __forceinline__ unsigned short f2bf(float f) {
  union { float f; unsigned int i; } v; v.f = f;
  unsigned int x = v.i;
  return (unsigned short)((x + 0x7fffu + ((x >> 16) & 1u)) >> 16);  // RNE
}
__device__ __forceinline__ void fsplit(float v, unsigned short& hi, unsigned short& lo) {
  hi = f2bf(v);
  lo = f2bf(v - bf2f(hi));
}

// fp32 register-tiled GEMM core (precompute only)
__device__ __forceinline__ void gemm_tile(const float* __restrict__ sA,
                                          const float* __restrict__ W,
                                          int lane_j, int rg, float acc[8][4]) {
#pragma unroll
  for (int mm = 0; mm < 8; mm++)
#pragma unroll
    for (int cc = 0; cc < 4; cc++) acc[mm][cc] = 0.f;
  for (int k = 0; k < H; k += 4) {
    float tvf[8][4];
#pragma unroll
    for (int mm = 0; mm < 8; mm++)
      *(float4*)&tvf[mm][0] = *(const float4*)&sA[(rg * 8 + mm) * H + k];
#pragma unroll
    for (int kk = 0; kk < 4; kk++) {
      const float* wr = W + (k + kk) * H + lane_j;
      float w0 = wr[0], w1 = wr[64], w2 = wr[128], w3 = wr[192];
#pragma unroll
      for (int mm = 0; mm < 8; mm++) {
        float av = tvf[mm][kk];
        acc[mm][0] = fmaf(av, w0, acc[mm][0]);
        acc[mm][1] = fmaf(av, w1, acc[mm][1]);
        acc[mm][2] = fmaf(av, w2, acc[mm][2]);
        acc[mm][3] = fmaf(av, w3, acc[mm][3]);
      }
    }
  }
}

// ---------- precompute kernels ----------

__global__ void k_detect(const int* __restrict__ ei, int* __restrict__ flag) {
  if (threadIdx.x == 0 && blockIdx.x == 0)
    *flag = (ei[1] == 0 && ei[3] == 0 && ei[5] == 0 && ei[7] == 0) ? 1 : 0;
}

__global__ __launch_bounds__(256) void k_zero(float4* __restrict__ p, int n4) {
  int i = blockIdx.x * 256 + threadIdx.x;
  if (i < n4) p[i] = make_float4(0.f, 0.f, 0.f, 0.f);
}

// dst histogram
__global__ __launch_bounds__(256) void k_hist(
    const void* __restrict__ ei, const int* __restrict__ flag64,
    int* __restrict__ hist, int E) {
  int e = blockIdx.x * 256 + threadIdx.x;
  if (e >= E) return;
  int d = (*flag64) ? (int)((const long long*)ei)[(size_t)E + e]
                    : ((const int*)ei)[(size_t)E + e];
  atomicAdd(&hist[d], 1);
}

// exclusive prefix sum over hist[N] -> cursor[N] (single block, 256 threads)
__global__ __launch_bounds__(256) void k_scan(
    const int* __restrict__ hist, int* __restrict__ cursor, int N) {
  __shared__ int part[256];
  int tid = threadIdx.x;
  int chunk = (N + 255) / 256;
  int s = 0;
  for (int i = 0; i < chunk; i++) {
    int idx = tid * chunk + i;
    if (idx < N) s += hist[idx];
  }
  part[tid] = s;
  __syncthreads();
  for (int off = 1; off < 256; off <<= 1) {
    int v = (tid >= off) ? part[tid - off] : 0;
    __syncthreads();
    part[tid] += v;
    __syncthreads();
  }
  int excl = (tid == 0) ? 0 : part[tid - 1];
  for (int i = 0; i < chunk; i++) {
    int idx = tid * chunk + i;
    if (idx < N) {
      cursor[idx] = excl;
      excl += hist[idx];
    }
  }
}

// scatter edges into dst-sorted order (src, dst, edge_attr)
__global__ __launch_bounds__(256) void k_scatter(
    const void* __restrict__ ei, const int* __restrict__ flag64,
    const float* __restrict__ ea, int* __restrict__ cursor,
    int* __restrict__ srcS, int* __restrict__ dstS, float* __restrict__ eaS, int E) {
  int e = blockIdx.x * 256 + threadIdx.x;
  if (e >= E) return;
  int is64 = *flag64;
  int s = is64 ? (int)((const long long*)ei)[e] : ((const int*)ei)[e];
  int d = is64 ? (int)((const long long*)ei)[(size_t)E + e]
               : ((const int*)ei)[(size_t)E + e];
  int p = atomicAdd(&cursor[d], 1);
  srcS[p] = s;
  dstS[p] = d;
  ((float4*)eaS)[p] = ((const float4*)ea)[e];
}

__global__ __launch_bounds__(256) void k_node_proj(
    const float* __restrict__ x, const int* __restrict__ a,
    const float* __restrict__ w, const float* __restrict__ b,
    float* __restrict__ h, int N) {
  int node = blockIdx.x;
  int j = threadIdx.x;
  float acc = b[j];
  acc = fmaf(x[node * 3 + 0], w[0 * H + j], acc);
  acc = fmaf(x[node * 3 + 1], w[1 * H + j], acc);
  acc = fmaf(x[node * 3 + 2], w[2 * H + j], acc);
  acc = fmaf((float)a[node], w[3 * H + j], acc);
  h[(size_t)node * H + j] = fmaxf(acc, 0.f);
}

// WtC[l][j][k] = (em_w2 @ lin_w[l])[k][j], hi/lo bf16 planes
__global__ __launch_bounds__(256, 2) void k_wcomb(
    const float* __restrict__ w2, const float* __restrict__ lin_w,
    unsigned short* __restrict__ wcTh, unsigned short* __restrict__ wcTl) {
  __shared__ __align__(16) float sA[32 * H];
  int l = blockIdx.x >> 3, tile = blockIdx.x & 7;
  int tid = threadIdx.x;
  const float4* src = (const float4*)(w2 + (size_t)tile * 32 * H);
#pragma unroll
  for (int it = 0; it < 8; it++) {
    int vi = it * 256 + tid;
    *(float4*)&sA[vi * 4] = src[vi];
  }
  __syncthreads();
  int lane_j = tid & 63, rg = tid >> 6;
  float acc[8][4];
  gemm_tile(sA, lin_w + (size_t)l * H * H, lane_j, rg, acc);
  unsigned short* oh = wcTh + (size_t)l * H * H;
  unsigned short* ol = wcTl + (size_t)l * H * H;
#pragma unroll
  for (int cc = 0; cc < 4; cc++) {
    int j = lane_j + 64 * cc;
#pragma unroll
    for (int mm = 0; mm < 8; mm++) {
      int k = tile * 32 + rg * 8 + mm;
      unsigned short hi, lo;
      fsplit(acc[mm][cc], hi, lo);
      oh[(size_t)j * H + k] = hi;
      ol[(size_t)j * H + k] = lo;
    }
  }
}

// beta[l] = em_b2 @ lin_w[l] + lin_b[l]
__global__ __launch_bounds__(256) void k_beta(
    const float* __restrict__ lin_w, const float* __restrict__ lin_b,
    const float* __restrict__ b2, float* __restrict__ beta) {
  int l = blockIdx.x, j = threadIdx.x;
  const float* W = lin_w + (size_t)l * H * H;
  float v = lin_b[l * H + j];
  for (int k = 0; k < H; k++) v = fmaf(b2[k], W[k * H + j], v);
  beta[l * H + j] = v;
}

// out_{h,l}[l][n][k] = bf16split(in[l][k][n])
__global__ __launch_bounds__(256) void k_transp(
    const float* __restrict__ in,
    unsigned short* __restrict__ outh, unsigned short* __restrict__ outl) {
  int l = blockIdx.z;
  int kb = blockIdx.x * 64, nb = blockIdx.y * 64;
  int tid = threadIdx.x;
  __shared__ float T[64][65];
  const float* src = in + (size_t)l * H * H;
#pragma unroll
  for (int it = 0; it < 16; it++) {
    int idx = it * 256 + tid;
    int kl = idx >> 6, nl = idx & 63;
    T[kl][nl] = src[(size_t)(kb + kl) * H + nb + nl];
  }
  __syncthreads();
  unsigned short* dh = outh + (size_t)l * H * H;
  unsigned short* dl = outl + (size_t)l * H * H;
#pragma unroll
  for (int it = 0; it < 8; it++) {
    int u = it * 256 + tid;
    int nl = u >> 5, k2 = (u & 31) * 2;
    unsigned short h0, l0, h1, l1;
    fsplit(T[k2][nl], h0, l0);
    fsplit(T[k2 + 1][nl], h1, l1);
    size_t o = (size_t)(nb + nl) * H + kb + k2;
    *(unsigned int*)&dh[o] = (unsigned int)h0 | ((unsigned int)h1 << 16);
    *(unsigned int*)&dl[o] = (unsigned int)l0 | ((unsigned int)l1 << 16);
  }
}

// ---------- per-layer MFMA kernels ----------

// Edge (dst-sorted), tile = TE(32) edges x 256 cols, 4 waves.
// Wave wv owns col-groups wv*4..wv*4+3 x BOTH 16-row groups -> each Wt element
// read exactly once per tile. h-gather prefetched before t-compute.
__global__ __launch_bounds__(256) void k_edge_mfma(
    const float* __restrict__ eaS,
    const float* __restrict__ w1, const float* __restrict__ b1,
    const unsigned short* __restrict__ Wth, const unsigned short* __restrict__ Wtl,
    const float* __restrict__ beta,
    const float* __restrict__ h, float* __restrict__ agg,
    const int* __restrict__ srcS, const int* __restrict__ dstS) {
  __shared__ __align__(16) char smem[TE * PITCH * 2 * 2];  // 33792 B, aliased
  unsigned short* sAh = (unsigned short*)smem;
  unsigned short* sAl = sAh + TE * PITCH;
  float* elbuf = (float*)smem;                             // TE*ELP*4 = 33280 B
  __shared__ __align__(16) float sEA[TE * 4];
  __shared__ int sSrc[TE];
  __shared__ int sDst[TE];
  int tid = threadIdx.x;
  int base = blockIdx.x * TE;
  if (tid < TE) {
    sSrc[tid] = srcS[base + tid];
  } else if (tid < 2 * TE) {
    sDst[tid - TE] = dstS[base + tid - TE];
  } else if (tid < 3 * TE) {
    // sEA holds TE*4 floats = TE float4s -> needs TE staging threads.
    // (R7 bug: TE/2 threads staged only half; rows 16..31 read garbage.)
    int t = tid - 2 * TE;
    ((float4*)sEA)[t] = ((const float4*)(eaS + (size_t)base * 4))[t];
  }
  __syncthreads();
  // ---- prefetch h-gather: 32 independent loads in flight through all phases
  float hv[TE];
#pragma unroll
  for (int m = 0; m < TE; m++) hv[m] = h[(size_t)sSrc[m] * H + tid];
  {  // t = relu(eaS @ w1 + b1) -> split bf16 LDS (col pair, 16 rows per thread)
    int j2 = (tid & 127) * 2;
    int r0 = (tid >> 7) * 16;
    float wv0[4], wv1[4];
#pragma unroll
    for (int q = 0; q < 4; q++) { wv0[q] = w1[q * H + j2]; wv1[q] = w1[q * H + j2 + 1]; }
    float bb0 = b1[j2], bb1 = b1[j2 + 1];
#pragma unroll
    for (int m = r0; m < r0 + 16; m++) {
      float t0 = bb0, t1 = bb1;
#pragma unroll
      for (int q = 0; q < 4; q++) {
        float eav = sEA[m * 4 + q];
        t0 = fmaf(eav, wv0[q], t0);
        t1 = fmaf(eav, wv1[q], t1);
      }
      t0 = fmaxf(t0, 0.f); t1 = fmaxf(t1, 0.f);
      unsigned short h0, l0, h1, l1;
      fsplit(t0, h0, l0);
      fsplit(t1, h1, l1);
      *(unsigned int*)&sAh[m * PITCH + j2] = (unsigned int)h0 | ((unsigned int)h1 << 16);
      *(unsigned int*)&sAl[m * PITCH + j2] = (unsigned int)l0 | ((unsigned int)l1 << 16);
    }
  }
  __syncthreads();
  int lane = tid & 63, wv = tid >> 6;
  int lane15 = lane & 15, quad = lane >> 4;
  int cg0 = wv * 4;            // wave's 4 col-groups (64 cols)
  f32x4 acc[2][4];
#pragma unroll
  for (int i = 0; i < 2; i++)
#pragma unroll
    for (int c = 0; c < 4; c++) acc[i][c] = (f32x4){0.f, 0.f, 0.f, 0.f};
  const unsigned short* a0h = sAh + lane15 * PITCH + quad * 8;
  const unsigned short* a0l = sAl + lane15 * PITCH + quad * 8;
  const unsigned short* bh = Wth + (size_t)(cg0 * 16 + lane15) * H + quad * 8;
  const unsigned short* bl = Wtl + (size_t)(cg0 * 16 + lane15) * H + quad * 8;
#pragma unroll
  for (int st = 0; st < 8; st++) {
    bf16x8 a0hf = *(const bf16x8*)(a0h + st * 32);
    bf16x8 a0lf = *(const bf16x8*)(a0l + st * 32);
    bf16x8 a1hf = *(const bf16x8*)(a0h + 16 * PITCH + st * 32);
    bf16x8 a1lf = *(const bf16x8*)(a0l + 16 * PITCH + st * 32);
#pragma unroll
    for (int cg = 0; cg < 4; cg++) {
      bf16x8 bhf = *(const bf16x8*)(bh + (size_t)cg * 16 * H + st * 32);
      bf16x8 blf = *(const bf16x8*)(bl + (size_t)cg * 16 * H + st * 32);
      acc[0][cg] = __builtin_amdgcn_mfma_f32_16x16x32_bf16(a0hf, bhf, acc[0][cg], 0, 0, 0);
      acc[0][cg] = __builtin_amdgcn_mfma_f32_16x16x32_bf16(a0lf, bhf, acc[0][cg], 0, 0, 0);
      acc[0][cg] = __builtin_amdgcn_mfma_f32_16x16x32_bf16(a0hf, blf, acc[0][cg], 0, 0, 0);
      acc[1][cg] = __builtin_amdgcn_mfma_f32_16x16x32_bf16(a1hf, bhf, acc[1][cg], 0, 0, 0);
      acc[1][cg] = __builtin_amdgcn_mfma_f32_16x16x32_bf16(a1lf, bhf, acc[1][cg], 0, 0, 0);
      acc[1][cg] = __builtin_amdgcn_mfma_f32_16x16x32_bf16(a1hf, blf, acc[1][cg], 0, 0, 0);
    }
  }
  float bv[4];
#pragma unroll
  for (int cg = 0; cg < 4; cg++) bv[cg] = beta[(cg0 + cg) * 16 + lane15];
  __syncthreads();  // all waves done reading sAh/sAl; smem becomes elbuf
#pragma unroll
  for (int rgi = 0; rgi < 2; rgi++) {
#pragma unroll
    for (int r = 0; r < 4; r++) {
      int row = rgi * 16 + quad * 4 + r;
#pragma unroll
      for (int cg = 0; cg < 4; cg++) {
        int j = (cg0 + cg) * 16 + lane15;
        elbuf[row * ELP + j] = acc[rgi][cg][r] + bv[cg];
      }
    }
  }
  __syncthreads();
  // segment-reduced scatter: thread j walks TE dst-sorted rows of col j.
  // dst-transition branch is block-uniform.
  {
    int j = tid;
    float run = 0.f;
    int prev = sDst[0];
#pragma unroll
    for (int m = 0; m < TE; m++) {
      int d = sDst[m];
      float msg = fmaxf(hv[m] + elbuf[m * ELP + j], 0.f);
      if (d != prev) {
        atomicAdd(&agg[(size_t)prev * H + j], run);
        run = 0.f;
        prev = d;
      }
      run += msg;
    }
    atomicAdd(&agg[(size_t)prev * H + j], run);
  }
}

// Node: z=h+agg; z1=relu(z@w1+b1); z2=z1@w2+b2; LN; h += relu(LN).
__global__ __launch_bounds__(256) void k_node_mfma(
    float* __restrict__ h, const float* __restrict__ agg,
    const unsigned short* __restrict__ w1Th, const unsigned short* __restrict__ w1Tl,
    const float* __restrict__ b1,
    const unsigned short* __restrict__ w2Th, const unsigned short* __restrict__ w2Tl,
    const float* __restrict__ b2,
    const float* __restrict__ lng, const float* __restrict__ lnb) {
  __shared__ __align__(16) unsigned short sAh[64 * PITCH];
  __shared__ __align__(16) unsigned short sAl[64 * PITCH];
  int tid = threadIdx.x;
  int base = blockIdx.x * 64;
  const float4* h4 = (const float4*)(h + (size_t)base * H);
  const float4* a4 = (const float4*)(agg + (size_t)base * H);
#pragma unroll
  for (int it = 0; it < 16; it++) {  // all 64 rows (4096 float4)
    int vi = it * 256 + tid;
    int row = vi >> 6, c4 = (vi & 63) * 4;
    float4 hv = h4[vi], av = a4[vi];
    float z[4] = {hv.x + av.x, hv.y + av.y, hv.z + av.z, hv.w + av.w};
    unsigned short hh[4], ll[4];
#pragma unroll
    for (int q = 0; q < 4; q++) fsplit(z[q], hh[q], ll[q]);
    uint2 uh, ul;
    uh.x = (unsigned int)hh[0] | ((unsigned int)hh[1] << 16);
    uh.y = (unsigned int)hh[2] | ((unsigned int)hh[3] << 16);
    ul.x = (unsigned int)ll[0] | ((unsigned int)ll[1] << 16);
    ul.y = (unsigned int)ll[2] | ((unsigned int)ll[3] << 16);
    *(uint2*)&sAh[row * PITCH + c4] = uh;
    *(uint2*)&sAl[row * PITCH + c4] = ul;
  }
  __syncthreads();
  int lane = tid & 63, wv = tid >> 6;
  int lane15 = lane & 15, quad = lane >> 4;
  const unsigned short* aph = sAh + (wv * 16 + lane15) * PITCH + quad * 8;
  const unsigned short* apl = sAl + (wv * 16 + lane15) * PITCH + quad * 8;
  f32x4 acc[16];
#pragma unroll
  for (int c = 0; c < 16; c++) acc[c] = (f32x4){0.f, 0.f, 0.f, 0.f};
  {
    const unsigned short* bph = w1Th + (size_t)lane15 * H + quad * 8;
    const unsigned short* bpl = w1Tl + (size_t)lane15 * H + quad * 8;
#pragma unroll
    for (int st = 0; st < 8; st++) {
      bf16x8 ahf = *(const bf16x8*)(aph + st * 32);
      bf16x8 alf = *(const bf16x8*)(apl + st * 32);
#pragma unroll
      for (int cg = 0; cg < 16; cg++) {
        bf16x8 bhf = *(const bf16x8*)(bph + (size_t)cg * 16 * H + st * 32);
        bf16x8 blf = *(const bf16x8*)(bpl + (size_t)cg * 16 * H + st * 32);
        acc[cg] = __builtin_amdgcn_mfma_f32_16x16x32_bf16(ahf, bhf, acc[cg], 0, 0, 0);
        acc[cg] = __builtin_amdgcn_mfma_f32_16x16x32_bf16(alf, bhf, acc[cg], 0, 0, 0);
        acc[cg] = __builtin_amdgcn_mfma_f32_16x16x32_bf16(ahf, blf, acc[cg], 0, 0, 0);
      }
    }
  }
  __syncthreads();
#pragma unroll
  for (int cg = 0; cg < 16; cg++) {
    float bb = b1[cg * 16 + lane15];
#pragma unroll
    for (int r = 0; r < 4; r++) {
      int row = wv * 16 + quad * 4 + r;
      float z1 = fmaxf(acc[cg][r] + bb, 0.f);
      unsigned short hh, ll;
      fsplit(z1, hh, ll);
      sAh[row * PITCH + cg * 16 + lane15] = hh;
      sAl[row * PITCH + cg * 16 + lane15] = ll;
    }
  }
  __syncthreads();
  f32x4 acc2[16];
#pragma unroll
  for (int c = 0; c < 16; c++) acc2[c] = (f32x4){0.f, 0.f, 0.f, 0.f};
  {
    const unsigned short* bph = w2Th + (size_t)lane15 * H + quad * 8;
    const unsigned short* bpl = w2Tl + (size_t)lane15 * H + quad * 8;
#pragma unroll
    for (int st = 0; st < 8; st++) {
      bf16x8 ahf = *(const bf16x8*)(aph + st * 32);
      bf16x8 alf = *(const bf16x8*)(apl + st * 32);
#pragma unroll
      for (int cg = 0; cg < 16; cg++) {
        bf16x8 bhf = *(const bf16x8*)(bph + (size_t)cg * 16 * H + st * 32);
        bf16x8 blf = *(const bf16x8*)(bpl + (size_t)cg * 16 * H + st * 32);
        acc2[cg] = __builtin_amdgcn_mfma_f32_16x16x32_bf16(ahf, bhf, acc2[cg], 0, 0, 0);
        acc2[cg] = __builtin_amdgcn_mfma_f32_16x16x32_bf16(alf, bhf, acc2[cg], 0, 0, 0);
        acc2[cg] = __builtin_amdgcn_mfma_f32_16x16x32_bf16(ahf, blf, acc2[cg], 0, 0, 0);
      }
    }
  }
  float b2v[16], gv[16], bbv[16];
#pragma unroll
  for (int cg = 0; cg < 16; cg++) {
    int j = cg * 16 + lane15;
    b2v[cg] = b2[j]; gv[cg] = lng[j]; bbv[cg] = lnb[j];
  }
#pragma unroll
  for (int r = 0; r < 4; r++) {
    float z2[16];
    float s = 0.f, ss = 0.f;
#pragma unroll
    for (int cg = 0; cg < 16; cg++) {
      z2[cg] = acc2[cg][r] + b2v[cg];
      s += z2[cg];
      ss = fmaf(z2[cg], z2[cg], ss);
    }
    s += __shfl_xor(s, 1, 64); ss += __shfl_xor(ss, 1, 64);
    s += __shfl_xor(s, 2, 64); ss += __shfl_xor(ss, 2, 64);
    s += __shfl_xor(s, 4, 64); ss += __shfl_xor(ss, 4, 64);
    s += __shfl_xor(s, 8, 64); ss += __shfl_xor(ss, 8, 64);
    float mu = s * (1.f / H);
    float var = ss * (1.f / H) - mu * mu;
    float rstd = rsqrtf(var + LN_EPS);
    int row = base + wv * 16 + quad * 4 + r;
    float* hr = h + (size_t)row * H;
#pragma unroll
    for (int cg = 0; cg < 16; cg++) {
      int j = cg * 16 + lane15;
      float v = fmaf((z2[cg] - mu) * rstd, gv[cg], bbv[cg]);
      hr[j] = hr[j] + fmaxf(v, 0.f);
    }
  }
}

// Mean-pool per graph + head MLP. One block per graph.
__global__ __launch_bounds__(256) void k_pool_head(
    const float* __restrict__ h,
    const float* __restrict__ w1, const float* __restrict__ b1,
    const float* __restrict__ w2, const float* __restrict__ b2,
    float* __restrict__ out, int n) {
  __shared__ float sG[H];
  __shared__ float sT[H];
  __shared__ float sR[4];
  int b = blockIdx.x, tid = threadIdx.x;
  const float* hb = h + (size_t)b * n * H;
  float a0 = 0.f, a1 = 0.f, a2 = 0.f, a3 = 0.f;
  for (int i = 0; i < n; i += 4) {
    a0 += hb[(size_t)(i + 0) * H + tid];
    a1 += hb[(size_t)(i + 1) * H + tid];
    a2 += hb[(size_t)(i + 2) * H + tid];
    a3 += hb[(size_t)(i + 3) * H + tid];
  }
  sG[tid] = (a0 + a1 + a2 + a3) / (float)n;
  __syncthreads();
  float t = b1[tid];
  for (int k = 0; k < H; k++) t = fmaf(sG[k], w1[k * H + tid], t);
  sT[tid] = fmaxf(t, 0.f);
  __syncthreads();
  float p = sT[tid] * w2[tid];
#pragma unroll
  for (int off = 32; off > 0; off >>= 1) p += __shfl_xor(p, off, 64);
  if ((tid & 63) == 0) sR[tid >> 6] = p;
  __syncthreads();
  if (tid == 0) out[b] = sR[0] + sR[1] + sR[2] + sR[3] + b2[0];
}

// ---------- launcher ----------
extern "C" void kernel_launch(void* const* d_in, const int* in_sizes, int n_in,
                              void* d_out, int out_size, void* d_ws, size_t ws_size,
                              hipStream_t stream) {
  const float* x      = (const float*)d_in[0];
  const float* ea     = (const float*)d_in[1];
  const void*  ei     = d_in[2];
  const int*   a      = (const int*)d_in[3];
  const float* np_w   = (const float*)d_in[4];
  const float* np_b   = (const float*)d_in[5];
  const float* em_w1  = (const float*)d_in[6];
  const float* em_b1  = (const float*)d_in[7];
  const float* em_w2  = (const float*)d_in[8];
  const float* em_b2  = (const float*)d_in[9];
  const float* lin_w  = (const float*)d_in[10];
  const float* lin_b  = (const float*)d_in[11];
  const float* m_w1   = (const float*)d_in[12];
  const float* m_b1   = (const float*)d_in[13];
  const float* m_w2   = (const float*)d_in[14];
  const float* m_b2   = (const float*)d_in[15];
  const float* ln_g   = (const float*)d_in[16];
  const float* ln_b   = (const float*)d_in[17];
  const float* hd_w1  = (const float*)d_in[18];
  const float* hd_b1  = (const float*)d_in[19];
  const float* hd_w2  = (const float*)d_in[20];
  const float* hd_b2  = (const float*)d_in[21];

  int N = in_sizes[0] / 3;
  int E = in_sizes[1] / 4;
  int B = out_size;
  int n = N / B;

  // workspace layout (~82 MB)
  char* ws = (char*)d_ws;
  size_t off = 0;
  auto alloc = [&](size_t bytes) {
    char* p = ws + off;
    off += (bytes + 255) & ~(size_t)255;
    return p;
  };
  float* h    = (float*)alloc((size_t)N * H * 4);
  float* agg  = (float*)alloc((size_t)N * H * 4);
  unsigned short* wcTh = (unsigned short*)alloc((size_t)3 * H * H * 2);
  unsigned short* wcTl = (unsigned short*)alloc((size_t)3 * H * H * 2);
  unsigned short* w1Th = (unsigned short*)alloc((size_t)3 * H * H * 2);
  unsigned short* w1Tl = (unsigned short*)alloc((size_t)3 * H * H * 2);
  unsigned short* w2Th = (unsigned short*)alloc((size_t)3 * H * H * 2);
  unsigned short* w2Tl = (unsigned short*)alloc((size_t)3 * H * H * 2);
  float* beta  = (float*)alloc(3 * H * 4);
  int*   flag  = (int*)alloc(4);
  int*   hist  = (int*)alloc((size_t)N * 4);
  int*   curs  = (int*)alloc((size_t)N * 4);
  int*   srcS  = (int*)alloc((size_t)E * 4);
  int*   dstS  = (int*)alloc((size_t)E * 4);
  float* eaS   = (float*)alloc((size_t)E * 4 * 4);

  float* out = (float*)d_out;
  int ebl = (E + 255) / 256;

  k_detect<<<1, 64, 0, stream>>>((const int*)ei, flag);
  k_zero<<<(N + 1023) / 1024, 256, 0, stream>>>((float4*)hist, N / 4);
  k_hist<<<ebl, 256, 0, stream>>>(ei, flag, hist, E);
  k_scan<<<1, 256, 0, stream>>>(hist, curs, N);
  k_scatter<<<ebl, 256, 0, stream>>>(ei, flag, ea, curs, srcS, dstS, eaS, E);
  k_node_proj<<<N, 256, 0, stream>>>(x, a, np_w, np_b, h, N);
  k_wcomb<<<24, 256, 0, stream>>>(em_w2, lin_w, wcTh, wcTl);
  k_beta<<<3, 256, 0, stream>>>(lin_w, lin_b, em_b2, beta);
  k_transp<<<dim3(4, 4, 3), 256, 0, stream>>>(m_w1, w1Th, w1Tl);
  k_transp<<<dim3(4, 4, 3), 256, 0, stream>>>(m_w2, w2Th, w2Tl);

  int n4 = N * H / 4;
  for (int l = 0; l < 3; l++) {
    k_zero<<<(n4 + 255) / 256, 256, 0, stream>>>((float4*)agg, n4);
    k_edge_mfma<<<E / TE, 256, 0, stream>>>(eaS, em_w1, em_b1,
                                            wcTh + (size_t)l * H * H,
                                            wcTl + (size_t)l * H * H,
                                            beta + (size_t)l * H,
                                            h, agg, srcS, dstS);
    k_node_mfma<<<N / 64, 256, 0, stream>>>(h, agg,
                                            w1Th + (size_t)l * H * H,
                                            w1Tl + (size_t)l * H * H,
                                            m_b1 + (size_t)l * H,
                                            w2Th + (size_t)l * H * H,
                                            w2Tl + (size_t)l * H * H,
                                            m_b2 + (size_t)l * H,
                                            ln_g + (size_t)l * H, ln_b + (size_t)l * H);
  }
  k_pool_head<<<B, 256, 0, stream>>>(h, hd_w1, hd_b1, hd_w2, hd_b2, out, n);
}